// Round 1
// baseline (557.000 us; speedup 1.0000x reference)
//
#include <hip/hip_runtime.h>
#include <hip/hip_bf16.h>
#include <math.h>

#define S_LEN 4096
#define B_SZ  4
#define D_DIM 1024
#define NHEAD 16
#define R_ROWS (S_LEN * B_SZ)   // 16384

typedef __bf16 bf16_t;
typedef __attribute__((ext_vector_type(8))) __bf16 bf16x8;
typedef __attribute__((ext_vector_type(4))) __bf16 bf16x4;
typedef __attribute__((ext_vector_type(4))) float  f32x4;

// ---------------- stage 0: fp32 -> bf16 convert ----------------
__global__ void k_cvt(const float* __restrict__ src, bf16_t* __restrict__ dst, int n) {
  int i = (blockIdx.x * 256 + threadIdx.x) * 4;
  if (i >= n) return;
  f32x4 v = *(const f32x4*)(src + i);
  bf16x4 o;
  o[0] = (bf16_t)v[0]; o[1] = (bf16_t)v[1]; o[2] = (bf16_t)v[2]; o[3] = (bf16_t)v[3];
  *(bf16x4*)(dst + i) = o;
}

// ---------------- stage 1: fused QKV projection + norm/elu ----------------
// grid (R_ROWS/64, NHEAD), 256 threads (4 waves). Tile: 64 rows x 64 cols (one head).
// C[m][col] = sum_k h[m][k] * W[col][k]  (NT GEMM, both operands row-major [.,K])
__global__ __launch_bounds__(256) void k_proj(
    const bf16_t* __restrict__ hB,
    const bf16_t* __restrict__ WqB, const bf16_t* __restrict__ WkB, const bf16_t* __restrict__ WvB,
    const float* __restrict__ bq, const float* __restrict__ bk, const float* __restrict__ bv,
    float* __restrict__ outV, float* __restrict__ outK, float* __restrict__ outQ)
{
  const int rt = blockIdx.x, n = blockIdx.y;
  const int row0 = rt * 64;
  const int tid = threadIdx.x;
  const int w = tid >> 6, l = tid & 63;
  const int lr = l & 15, lg = l >> 4;

  __shared__ bf16_t sA [64][72];
  __shared__ bf16_t sWq[64][72];
  __shared__ bf16_t sWk[64][72];
  __shared__ bf16_t sWv[64][72];

  f32x4 aq[4], ak[4], av[4];
  #pragma unroll
  for (int c = 0; c < 4; c++)
    #pragma unroll
    for (int r = 0; r < 4; r++) { aq[c][r] = 0.f; ak[c][r] = 0.f; av[c][r] = 0.f; }

  const int sr = tid >> 3;        // 0..31
  const int sc = (tid & 7) * 8;   // 0..56

  for (int k0 = 0; k0 < D_DIM; k0 += 64) {
    #pragma unroll
    for (int p = 0; p < 2; p++) {
      const int r = sr + p * 32;
      *(uint4*)&sA [r][sc] = *(const uint4*)&hB [(size_t)(row0 + r) * D_DIM + k0 + sc];
      *(uint4*)&sWq[r][sc] = *(const uint4*)&WqB[(size_t)(n * 64 + r) * D_DIM + k0 + sc];
      *(uint4*)&sWk[r][sc] = *(const uint4*)&WkB[(size_t)(n * 64 + r) * D_DIM + k0 + sc];
      *(uint4*)&sWv[r][sc] = *(const uint4*)&WvB[(size_t)(n * 64 + r) * D_DIM + k0 + sc];
    }
    __syncthreads();
    #pragma unroll
    for (int kk = 0; kk < 64; kk += 32) {
      bf16x8 af = *(const bf16x8*)&sA[w * 16 + lr][kk + lg * 8];
      #pragma unroll
      for (int c = 0; c < 4; c++) {
        bf16x8 bq_ = *(const bf16x8*)&sWq[c * 16 + lr][kk + lg * 8];
        aq[c] = __builtin_amdgcn_mfma_f32_16x16x32_bf16(af, bq_, aq[c], 0, 0, 0);
        bf16x8 bk_ = *(const bf16x8*)&sWk[c * 16 + lr][kk + lg * 8];
        ak[c] = __builtin_amdgcn_mfma_f32_16x16x32_bf16(af, bk_, ak[c], 0, 0, 0);
        bf16x8 bv_ = *(const bf16x8*)&sWv[c * 16 + lr][kk + lg * 8];
        av[c] = __builtin_amdgcn_mfma_f32_16x16x32_bf16(af, bv_, av[c], 0, 0, 0);
      }
    }
    __syncthreads();
  }

  // epilogue: bias, unitnorm (q,k), elu (k). C layout: col = lr, row = lg*4 + reg.
  #pragma unroll
  for (int r = 0; r < 4; r++) {
    const int m = row0 + w * 16 + lg * 4 + r;
    float qv[4], kv[4], vv[4];
    float sq = 0.f, sk2 = 0.f;
    #pragma unroll
    for (int c = 0; c < 4; c++) {
      const int col = c * 16 + lr;
      qv[c] = aq[c][r] + bq[n * 64 + col];
      kv[c] = ak[c][r] + bk[n * 64 + col];
      vv[c] = av[c][r] + bv[n * 64 + col];
      sq  += qv[c] * qv[c];
      sk2 += kv[c] * kv[c];
    }
    #pragma unroll
    for (int msk = 1; msk < 16; msk <<= 1) {
      sq  += __shfl_xor(sq,  msk);
      sk2 += __shfl_xor(sk2, msk);
    }
    const float rq = 1.0f / sqrtf(sq);
    const float rk = 1.0f / sqrtf(sk2);
    #pragma unroll
    for (int c = 0; c < 4; c++) {
      const size_t g = (size_t)m * D_DIM + n * 64 + c * 16 + lr;
      const float qn = qv[c] * rq;
      float kn = kv[c] * rk;
      kn = kn > 0.f ? kn : expm1f(kn);
      outQ[g] = qn;
      outK[g] = kn;
      outV[g] = vv[c];
    }
  }
}

// ---------------- stage 2: A[b,n,v,q] partials = sum_s v*k ----------------
// grid (64 = b*16+n, 8 s-chunks), 256 threads
__global__ __launch_bounds__(256) void k_state(
    const float* __restrict__ Kf, const float* __restrict__ Vf,
    float* __restrict__ Apart)
{
  const int bn = blockIdx.x;
  const int ch = blockIdx.y;
  const int b = bn >> 4, n = bn & 15;
  const int tid = threadIdx.x;
  const int ti = tid >> 4, tj = tid & 15;

  __shared__ float sV[32][64];
  __shared__ float sK[32][64];

  float acc[4][4];
  #pragma unroll
  for (int i = 0; i < 4; i++)
    #pragma unroll
    for (int j = 0; j < 4; j++) acc[i][j] = 0.f;

  for (int s0 = ch * 512; s0 < ch * 512 + 512; s0 += 32) {
    #pragma unroll
    for (int p = 0; p < 8; p++) {
      const int ii = tid + p * 256;
      const int rr = ii >> 6, cc = ii & 63;
      const size_t g = (size_t)((s0 + rr) * B_SZ + b) * D_DIM + n * 64 + cc;
      sV[rr][cc] = Vf[g];
      sK[rr][cc] = Kf[g];
    }
    __syncthreads();
    #pragma unroll
    for (int ss = 0; ss < 32; ss++) {
      f32x4 vv = *(const f32x4*)&sV[ss][ti * 4];
      f32x4 kk = *(const f32x4*)&sK[ss][tj * 4];
      #pragma unroll
      for (int i = 0; i < 4; i++)
        #pragma unroll
        for (int j = 0; j < 4; j++)
          acc[i][j] = fmaf(vv[i], kk[j], acc[i][j]);
    }
    __syncthreads();
  }
  float* ap = Apart + ((size_t)ch * 64 + bn) * 4096;
  #pragma unroll
  for (int i = 0; i < 4; i++)
    #pragma unroll
    for (int j = 0; j < 4; j++)
      ap[(ti * 4 + i) * 64 + tj * 4 + j] = acc[i][j];
}

// ---------------- stage 3: out_attn[s,v] = sum_q q[s,q] * A[v,q] ----------------
// grid (S/64, 64 = b*16+n), 256 threads
__global__ __launch_bounds__(256) void k_apply(
    const float* __restrict__ Qf, const float* __restrict__ Apart,
    bf16_t* __restrict__ OA)
{
  const int st = blockIdx.x;
  const int bn = blockIdx.y;
  const int b = bn >> 4, n = bn & 15;
  const int tid = threadIdx.x;
  const int ti = tid >> 4, tj = tid & 15;

  __shared__ float sA[64][65];
  __shared__ float sQ[64][65];

  #pragma unroll
  for (int p = 0; p < 16; p++) {
    const int ii = tid + p * 256;
    const int vi = ii >> 6, qj = ii & 63;
    float s = 0.f;
    #pragma unroll
    for (int c2 = 0; c2 < 8; c2++)
      s += Apart[((size_t)c2 * 64 + bn) * 4096 + ii];
    sA[vi][qj] = s;
    sQ[vi][qj] = Qf[(size_t)((st * 64 + vi) * B_SZ + b) * D_DIM + n * 64 + qj];
  }
  __syncthreads();

  float acc[4][4];
  #pragma unroll
  for (int i = 0; i < 4; i++)
    #pragma unroll
    for (int j = 0; j < 4; j++) acc[i][j] = 0.f;

  #pragma unroll 4
  for (int qq = 0; qq < 64; qq++) {
    float qv[4], av[4];
    #pragma unroll
    for (int i = 0; i < 4; i++) qv[i] = sQ[ti * 4 + i][qq];
    #pragma unroll
    for (int j = 0; j < 4; j++) av[j] = sA[tj * 4 + j][qq];
    #pragma unroll
    for (int i = 0; i < 4; i++)
      #pragma unroll
      for (int j = 0; j < 4; j++)
        acc[i][j] = fmaf(qv[i], av[j], acc[i][j]);
  }
  #pragma unroll
  for (int i = 0; i < 4; i++)
    #pragma unroll
    for (int j = 0; j < 4; j++)
      OA[(size_t)((st * 64 + ti * 4 + i) * B_SZ + b) * D_DIM + n * 64 + tj * 4 + j] =
          (bf16_t)acc[i][j];
}

// ---------------- stage 4: out = OA @ Wo^T + bo ----------------
// grid (R_ROWS/64, D/64), 256 threads
__global__ __launch_bounds__(256) void k_out(
    const bf16_t* __restrict__ OAB, const bf16_t* __restrict__ WoB,
    const float* __restrict__ bo, float* __restrict__ outO)
{
  const int rt = blockIdx.x, nt = blockIdx.y;
  const int row0 = rt * 64;
  const int tid = threadIdx.x;
  const int w = tid >> 6, l = tid & 63;
  const int lr = l & 15, lg = l >> 4;

  __shared__ bf16_t sA[64][72];
  __shared__ bf16_t sB[64][72];

  f32x4 acc[4];
  #pragma unroll
  for (int c = 0; c < 4; c++)
    #pragma unroll
    for (int r = 0; r < 4; r++) acc[c][r] = 0.f;

  const int sr = tid >> 3;
  const int sc = (tid & 7) * 8;

  for (int k0 = 0; k0 < D_DIM; k0 += 64) {
    #pragma unroll
    for (int p = 0; p < 2; p++) {
      const int r = sr + p * 32;
      *(uint4*)&sA[r][sc] = *(const uint4*)&OAB[(size_t)(row0 + r) * D_DIM + k0 + sc];
      *(uint4*)&sB[r][sc] = *(const uint4*)&WoB[(size_t)(nt * 64 + r) * D_DIM + k0 + sc];
    }
    __syncthreads();
    #pragma unroll
    for (int kk = 0; kk < 64; kk += 32) {
      bf16x8 af = *(const bf16x8*)&sA[w * 16 + lr][kk + lg * 8];
      #pragma unroll
      for (int c = 0; c < 4; c++) {
        bf16x8 bf = *(const bf16x8*)&sB[c * 16 + lr][kk + lg * 8];
        acc[c] = __builtin_amdgcn_mfma_f32_16x16x32_bf16(af, bf, acc[c], 0, 0, 0);
      }
    }
    __syncthreads();
  }

  #pragma unroll
  for (int r = 0; r < 4; r++) {
    const int m = row0 + w * 16 + lg * 4 + r;
    #pragma unroll
    for (int c = 0; c < 4; c++) {
      const int col = nt * 64 + c * 16 + lr;
      outO[(size_t)m * D_DIM + col] = acc[c][r] + bo[col];
    }
  }
}

extern "C" void kernel_launch(void* const* d_in, const int* in_sizes, int n_in,
                              void* d_out, int out_size, void* d_ws, size_t ws_size,
                              hipStream_t stream) {
  (void)in_sizes; (void)n_in; (void)out_size; (void)ws_size;
  const float* h  = (const float*)d_in[0];
  const float* Wq = (const float*)d_in[1];
  const float* bq = (const float*)d_in[2];
  const float* Wk = (const float*)d_in[3];
  const float* bk = (const float*)d_in[4];
  const float* Wv = (const float*)d_in[5];
  const float* bv = (const float*)d_in[6];
  const float* Wo = (const float*)d_in[7];
  const float* bo = (const float*)d_in[8];

  float* out0 = (float*)d_out;                       // final out (holds V temporarily)
  float* outK = out0 + (size_t)R_ROWS * D_DIM;       // k
  float* outQ = outK + (size_t)R_ROWS * D_DIM;       // q

  char* ws = (char*)d_ws;
  bf16_t* hB    = (bf16_t*)ws;                                        // 32 MB
  bf16_t* WqB   = (bf16_t*)(ws + 33554432);                           // 2 MB
  bf16_t* WkB   = (bf16_t*)(ws + 33554432 + 2097152);
  bf16_t* WvB   = (bf16_t*)(ws + 33554432 + 2 * 2097152);
  bf16_t* WoB   = (bf16_t*)(ws + 33554432 + 3 * 2097152);
  float*  Apart = (float*)(ws + 33554432 + 4 * 2097152);              // 8 MB
  bf16_t* OAB   = (bf16_t*)(ws + 33554432 + 4 * 2097152 + 8388608);   // 32 MB

  const int nH = R_ROWS * D_DIM;   // 16777216
  const int nW = D_DIM * D_DIM;    // 1048576
  k_cvt<<<nH / 1024, 256, 0, stream>>>(h, hB, nH);
  k_cvt<<<nW / 1024, 256, 0, stream>>>(Wq, WqB, nW);
  k_cvt<<<nW / 1024, 256, 0, stream>>>(Wk, WkB, nW);
  k_cvt<<<nW / 1024, 256, 0, stream>>>(Wv, WvB, nW);
  k_cvt<<<nW / 1024, 256, 0, stream>>>(Wo, WoB, nW);

  k_proj<<<dim3(R_ROWS / 64, NHEAD), 256, 0, stream>>>(hB, WqB, WkB, WvB, bq, bk, bv,
                                                       out0, outK, outQ);
  k_state<<<dim3(64, 8), 256, 0, stream>>>(outK, out0, Apart);
  k_apply<<<dim3(S_LEN / 64, 64), 256, 0, stream>>>(outQ, Apart, OAB);
  k_out<<<dim3(R_ROWS / 64, D_DIM / 64), 256, 0, stream>>>(OAB, WoB, bo, out0);
}

// Round 2
// 369.459 us; speedup vs baseline: 1.5076x; 1.5076x over previous
//
#include <hip/hip_runtime.h>
#include <hip/hip_bf16.h>
#include <math.h>

#define S_LEN 4096
#define B_SZ  4
#define D_DIM 1024
#define NHEAD 16
#define R_ROWS (S_LEN * B_SZ)   // 16384

#define AS1 __attribute__((address_space(1)))
#define AS3 __attribute__((address_space(3)))

typedef __bf16 bf16_t;
typedef __attribute__((ext_vector_type(8))) __bf16 bf16x8;
typedef __attribute__((ext_vector_type(4))) __bf16 bf16x4;
typedef __attribute__((ext_vector_type(4))) float  f32x4;

// async global->LDS, 16 bytes per lane. lptr must be wave-uniform base
// (HW writes lane i at lptr + i*16); gptr is per-lane.
__device__ __forceinline__ void gload16(const bf16_t* g, bf16_t* l) {
  __builtin_amdgcn_global_load_lds((const AS1 unsigned int*)g,
                                   (AS3 unsigned int*)l, 16, 0, 0);
}

// ---------------- stage 0: fp32 -> bf16 convert ----------------
__global__ void k_cvt(const float* __restrict__ src, bf16_t* __restrict__ dst, int n) {
  int i = (blockIdx.x * 256 + threadIdx.x) * 4;
  if (i >= n) return;
  f32x4 v = *(const f32x4*)(src + i);
  bf16x4 o;
  o[0] = (bf16_t)v[0]; o[1] = (bf16_t)v[1]; o[2] = (bf16_t)v[2]; o[3] = (bf16_t)v[3];
  *(bf16x4*)(dst + i) = o;
}

// ---------------- stage 1: fused QKV projection (m97 structure) ----------------
// C[16384, 3072] = h[16384,1024] @ Wcat[3072,1024]^T  (NT GEMM)
// grid (128, 24), 256 threads. 128x128 tile, BK=64, global_load_lds staging.
// bn 0..7 -> q cols, 8..15 -> k cols, 16..23 -> v cols.
// Each wave's 64-col sub-tile == one head's full 64-col norm group.
__global__ __launch_bounds__(256) void k_proj(
    const bf16_t* __restrict__ hB, const bf16_t* __restrict__ Wcat,
    const float* __restrict__ bq, const float* __restrict__ bk, const float* __restrict__ bv,
    float* __restrict__ outV, float* __restrict__ outK, float* __restrict__ outQ)
{
  __shared__ bf16_t sA[128 * 64];
  __shared__ bf16_t sB[128 * 64];

  const int tid  = threadIdx.x;
  const int wave = tid >> 6, lane = tid & 63;
  const int lr = lane & 15, lg = lane >> 4;
  const int wr = wave >> 1, wc = wave & 1;
  const int row0 = blockIdx.x * 128;
  const int bn   = blockIdx.y;
  const int col0 = bn * 128;            // row offset into Wcat

  f32x4 acc[4][4];
  #pragma unroll
  for (int m = 0; m < 4; m++)
    #pragma unroll
    for (int n = 0; n < 4; n++)
      #pragma unroll
      for (int r = 0; r < 4; r++) acc[m][n][r] = 0.f;

  for (int k0 = 0; k0 < D_DIM; k0 += 64) {
    #pragma unroll
    for (int j = 0; j < 4; ++j) {
      const int chunk = j * 256 + tid;          // 16B chunk index, row = chunk/8
      const int r = chunk >> 3, c8 = chunk & 7;
      bf16_t* ldsbase_a = &sA[(j * 256 + wave * 64) * 8];
      bf16_t* ldsbase_b = &sB[(j * 256 + wave * 64) * 8];
      gload16(&hB  [(size_t)(row0 + r) * D_DIM + k0 + c8 * 8], ldsbase_a);
      gload16(&Wcat[(size_t)(col0 + r) * D_DIM + k0 + c8 * 8], ldsbase_b);
    }
    __syncthreads();
    #pragma unroll
    for (int kk = 0; kk < 64; kk += 32) {
      bf16x8 af[4], bfr[4];
      #pragma unroll
      for (int m = 0; m < 4; ++m)
        af[m] = *(const bf16x8*)&sA[(wr * 64 + m * 16 + lr) * 64 + kk + lg * 8];
      #pragma unroll
      for (int n = 0; n < 4; ++n)
        bfr[n] = *(const bf16x8*)&sB[(wc * 64 + n * 16 + lr) * 64 + kk + lg * 8];
      #pragma unroll
      for (int m = 0; m < 4; ++m)
        #pragma unroll
        for (int n = 0; n < 4; ++n)
          acc[m][n] = __builtin_amdgcn_mfma_f32_16x16x32_bf16(af[m], bfr[n], acc[m][n], 0, 0, 0);
    }
    __syncthreads();
  }

  // epilogue. C frag layout: col = lr, row = lg*4 + reg.
  const int sec    = bn >> 3;                         // 0=q, 1=k, 2=v
  const int colIn0 = (bn & 7) * 128 + wc * 64;        // col within [0,1024)
  const float* bias = (sec == 0) ? bq : (sec == 1 ? bk : bv);
  float bvv[4];
  #pragma unroll
  for (int c = 0; c < 4; c++) bvv[c] = bias[colIn0 + c * 16 + lr];

  #pragma unroll
  for (int m = 0; m < 4; ++m) {
    #pragma unroll
    for (int r = 0; r < 4; ++r) {
      const int gm = row0 + wr * 64 + m * 16 + lg * 4 + r;
      float v[4];
      float ss = 0.f;
      #pragma unroll
      for (int c = 0; c < 4; c++) {
        v[c] = acc[m][c][r] + bvv[c];
        ss += v[c] * v[c];
      }
      if (sec == 2) {
        #pragma unroll
        for (int c = 0; c < 4; c++)
          outV[(size_t)gm * D_DIM + colIn0 + c * 16 + lr] = v[c];
      } else {
        #pragma unroll
        for (int msk = 1; msk < 16; msk <<= 1) ss += __shfl_xor(ss, msk);
        const float rs = 1.0f / sqrtf(ss);
        if (sec == 0) {
          #pragma unroll
          for (int c = 0; c < 4; c++)
            outQ[(size_t)gm * D_DIM + colIn0 + c * 16 + lr] = v[c] * rs;
        } else {
          #pragma unroll
          for (int c = 0; c < 4; c++) {
            float kn = v[c] * rs;
            kn = kn > 0.f ? kn : expm1f(kn);
            outK[(size_t)gm * D_DIM + colIn0 + c * 16 + lr] = kn;
          }
        }
      }
    }
  }
}

// ---------------- stage 2: A[b,n,v,q] partials = sum_s v*k ----------------
// grid (64 = b*16+n, 8 s-chunks), 256 threads
__global__ __launch_bounds__(256) void k_state(
    const float* __restrict__ Kf, const float* __restrict__ Vf,
    float* __restrict__ Apart)
{
  const int bn = blockIdx.x;
  const int ch = blockIdx.y;
  const int b = bn >> 4, n = bn & 15;
  const int tid = threadIdx.x;
  const int ti = tid >> 4, tj = tid & 15;

  __shared__ float sV[32][64];
  __shared__ float sK[32][64];

  float acc[4][4];
  #pragma unroll
  for (int i = 0; i < 4; i++)
    #pragma unroll
    for (int j = 0; j < 4; j++) acc[i][j] = 0.f;

  for (int s0 = ch * 512; s0 < ch * 512 + 512; s0 += 32) {
    #pragma unroll
    for (int p = 0; p < 8; p++) {
      const int ii = tid + p * 256;
      const int rr = ii >> 6, cc = ii & 63;
      const size_t g = (size_t)((s0 + rr) * B_SZ + b) * D_DIM + n * 64 + cc;
      sV[rr][cc] = Vf[g];
      sK[rr][cc] = Kf[g];
    }
    __syncthreads();
    #pragma unroll
    for (int ss = 0; ss < 32; ss++) {
      f32x4 vv = *(const f32x4*)&sV[ss][ti * 4];
      f32x4 kk = *(const f32x4*)&sK[ss][tj * 4];
      #pragma unroll
      for (int i = 0; i < 4; i++)
        #pragma unroll
        for (int j = 0; j < 4; j++)
          acc[i][j] = fmaf(vv[i], kk[j], acc[i][j]);
    }
    __syncthreads();
  }
  float* ap = Apart + ((size_t)ch * 64 + bn) * 4096;
  #pragma unroll
  for (int i = 0; i < 4; i++)
    #pragma unroll
    for (int j = 0; j < 4; j++)
      ap[(ti * 4 + i) * 64 + tj * 4 + j] = acc[i][j];
}

// ---------------- stage 3: out_attn[s,v] = sum_q q[s,q] * A[v,q] ----------------
// grid (S/64, 64 = b*16+n), 256 threads
__global__ __launch_bounds__(256) void k_apply(
    const float* __restrict__ Qf, const float* __restrict__ Apart,
    bf16_t* __restrict__ OA)
{
  const int st = blockIdx.x;
  const int bn = blockIdx.y;
  const int b = bn >> 4, n = bn & 15;
  const int tid = threadIdx.x;
  const int ti = tid >> 4, tj = tid & 15;

  __shared__ float sA[64][65];
  __shared__ float sQ[64][65];

  #pragma unroll
  for (int p = 0; p < 16; p++) {
    const int ii = tid + p * 256;
    const int vi = ii >> 6, qj = ii & 63;
    float s = 0.f;
    #pragma unroll
    for (int c2 = 0; c2 < 8; c2++)
      s += Apart[((size_t)c2 * 64 + bn) * 4096 + ii];
    sA[vi][qj] = s;
    sQ[vi][qj] = Qf[(size_t)((st * 64 + vi) * B_SZ + b) * D_DIM + n * 64 + qj];
  }
  __syncthreads();

  float acc[4][4];
  #pragma unroll
  for (int i = 0; i < 4; i++)
    #pragma unroll
    for (int j = 0; j < 4; j++) acc[i][j] = 0.f;

  #pragma unroll 4
  for (int qq = 0; qq < 64; qq++) {
    float qv[4], av[4];
    #pragma unroll
    for (int i = 0; i < 4; i++) qv[i] = sQ[ti * 4 + i][qq];
    #pragma unroll
    for (int j = 0; j < 4; j++) av[j] = sA[tj * 4 + j][qq];
    #pragma unroll
    for (int i = 0; i < 4; i++)
      #pragma unroll
      for (int j = 0; j < 4; j++)
        acc[i][j] = fmaf(qv[i], av[j], acc[i][j]);
  }
  #pragma unroll
  for (int i = 0; i < 4; i++)
    #pragma unroll
    for (int j = 0; j < 4; j++)
      OA[(size_t)((st * 64 + ti * 4 + i) * B_SZ + b) * D_DIM + n * 64 + tj * 4 + j] =
          (bf16_t)acc[i][j];
}

// ---------------- stage 4: out = OA @ Wo^T + bo (m97 structure) ----------------
// grid (128, 8), 256 threads, 128x128 tile, BK=64.
__global__ __launch_bounds__(256) void k_out(
    const bf16_t* __restrict__ OAB, const bf16_t* __restrict__ WoB,
    const float* __restrict__ bo, float* __restrict__ outO)
{
  __shared__ bf16_t sA[128 * 64];
  __shared__ bf16_t sB[128 * 64];

  const int tid  = threadIdx.x;
  const int wave = tid >> 6, lane = tid & 63;
  const int lr = lane & 15, lg = lane >> 4;
  const int wr = wave >> 1, wc = wave & 1;
  const int row0 = blockIdx.x * 128;
  const int col0 = blockIdx.y * 128;

  f32x4 acc[4][4];
  #pragma unroll
  for (int m = 0; m < 4; m++)
    #pragma unroll
    for (int n = 0; n < 4; n++)
      #pragma unroll
      for (int r = 0; r < 4; r++) acc[m][n][r] = 0.f;

  for (int k0 = 0; k0 < D_DIM; k0 += 64) {
    #pragma unroll
    for (int j = 0; j < 4; ++j) {
      const int chunk = j * 256 + tid;
      const int r = chunk >> 3, c8 = chunk & 7;
      bf16_t* ldsbase_a = &sA[(j * 256 + wave * 64) * 8];
      bf16_t* ldsbase_b = &sB[(j * 256 + wave * 64) * 8];
      gload16(&OAB[(size_t)(row0 + r) * D_DIM + k0 + c8 * 8], ldsbase_a);
      gload16(&WoB[(size_t)(col0 + r) * D_DIM + k0 + c8 * 8], ldsbase_b);
    }
    __syncthreads();
    #pragma unroll
    for (int kk = 0; kk < 64; kk += 32) {
      bf16x8 af[4], bfr[4];
      #pragma unroll
      for (int m = 0; m < 4; ++m)
        af[m] = *(const bf16x8*)&sA[(wr * 64 + m * 16 + lr) * 64 + kk + lg * 8];
      #pragma unroll
      for (int n = 0; n < 4; ++n)
        bfr[n] = *(const bf16x8*)&sB[(wc * 64 + n * 16 + lr) * 64 + kk + lg * 8];
      #pragma unroll
      for (int m = 0; m < 4; ++m)
        #pragma unroll
        for (int n = 0; n < 4; ++n)
          acc[m][n] = __builtin_amdgcn_mfma_f32_16x16x32_bf16(af[m], bfr[n], acc[m][n], 0, 0, 0);
    }
    __syncthreads();
  }

  #pragma unroll
  for (int m = 0; m < 4; ++m) {
    #pragma unroll
    for (int r = 0; r < 4; ++r) {
      const int gm = row0 + wr * 64 + m * 16 + lg * 4 + r;
      #pragma unroll
      for (int c = 0; c < 4; c++) {
        const int col = col0 + wc * 64 + c * 16 + lr;
        outO[(size_t)gm * D_DIM + col] = acc[m][c][r] + bo[col];
      }
    }
  }
}

extern "C" void kernel_launch(void* const* d_in, const int* in_sizes, int n_in,
                              void* d_out, int out_size, void* d_ws, size_t ws_size,
                              hipStream_t stream) {
  (void)in_sizes; (void)n_in; (void)out_size; (void)ws_size;
  const float* h  = (const float*)d_in[0];
  const float* Wq = (const float*)d_in[1];
  const float* bq = (const float*)d_in[2];
  const float* Wk = (const float*)d_in[3];
  const float* bk = (const float*)d_in[4];
  const float* Wv = (const float*)d_in[5];
  const float* bv = (const float*)d_in[6];
  const float* Wo = (const float*)d_in[7];
  const float* bo = (const float*)d_in[8];

  float* out0 = (float*)d_out;                       // final out (holds V temporarily)
  float* outK = out0 + (size_t)R_ROWS * D_DIM;       // k
  float* outQ = outK + (size_t)R_ROWS * D_DIM;       // q

  char* ws = (char*)d_ws;
  bf16_t* hB    = (bf16_t*)ws;                                 // 32 MB
  bf16_t* Wcat  = (bf16_t*)(ws + 33554432);                    // 6 MB: Wq|Wk|Wv rows
  bf16_t* WoB   = (bf16_t*)(ws + 33554432 + 6291456);          // 2 MB
  float*  Apart = (float*)(ws + 41943040);                     // 8 MB
  bf16_t* OAB   = (bf16_t*)(ws + 50331648);                    // 32 MB

  const int nH = R_ROWS * D_DIM;   // 16777216
  const int nW = D_DIM * D_DIM;    // 1048576
  k_cvt<<<nH / 1024, 256, 0, stream>>>(h, hB, nH);
  k_cvt<<<nW / 1024, 256, 0, stream>>>(Wq, Wcat, nW);
  k_cvt<<<nW / 1024, 256, 0, stream>>>(Wk, Wcat + nW, nW);
  k_cvt<<<nW / 1024, 256, 0, stream>>>(Wv, Wcat + 2 * nW, nW);
  k_cvt<<<nW / 1024, 256, 0, stream>>>(Wo, WoB, nW);

  k_proj<<<dim3(R_ROWS / 128, 24), 256, 0, stream>>>(hB, Wcat, bq, bk, bv,
                                                     out0, outK, outQ);
  k_state<<<dim3(64, 8), 256, 0, stream>>>(outK, out0, Apart);
  k_apply<<<dim3(S_LEN / 64, 64), 256, 0, stream>>>(outQ, Apart, OAB);
  k_out<<<dim3(R_ROWS / 128, D_DIM / 8 / 16), 256, 0, stream>>>(OAB, WoB, bo, out0);
}

// Round 3
// 358.990 us; speedup vs baseline: 1.5516x; 1.0292x over previous
//
#include <hip/hip_runtime.h>
#include <hip/hip_bf16.h>
#include <math.h>

#define S_LEN 4096
#define B_SZ  4
#define D_DIM 1024
#define NHEAD 16
#define R_ROWS (S_LEN * B_SZ)   // 16384

#define AS1 __attribute__((address_space(1)))
#define AS3 __attribute__((address_space(3)))

typedef __bf16 bf16_t;
typedef __attribute__((ext_vector_type(8))) __bf16 bf16x8;
typedef __attribute__((ext_vector_type(4))) __bf16 bf16x4;
typedef __attribute__((ext_vector_type(4))) float  f32x4;

// async global->LDS, 16 bytes per lane. lptr must be wave-uniform base
// (HW writes lane i at lptr + i*16); gptr is per-lane.
__device__ __forceinline__ void gload16(const bf16_t* g, bf16_t* l) {
  __builtin_amdgcn_global_load_lds((const AS1 unsigned int*)g,
                                   (AS3 unsigned int*)l, 16, 0, 0);
}

// ---------------- stage 0: fp32 -> bf16 convert ----------------
__global__ void k_cvt(const float* __restrict__ src, bf16_t* __restrict__ dst, int n) {
  int i = (blockIdx.x * 256 + threadIdx.x) * 4;
  if (i >= n) return;
  f32x4 v = *(const f32x4*)(src + i);
  bf16x4 o;
  o[0] = (bf16_t)v[0]; o[1] = (bf16_t)v[1]; o[2] = (bf16_t)v[2]; o[3] = (bf16_t)v[3];
  *(bf16x4*)(dst + i) = o;
}

// ---------------- stage 1: fused QKV projection (dbuf 2-phase) ----------------
// C[16384, 3072] = h[16384,1024] @ Wcat[3072,1024]^T  (NT GEMM)
// grid (128, 24), 256 threads. 128x128 tile, BK=64, double-buffered LDS,
// global_load_lds staging issued BEFORE compute, ONE barrier per K-step.
// bn 0..7 -> q cols, 8..15 -> k cols, 16..23 -> v cols.
__global__ __launch_bounds__(256) void k_proj(
    const bf16_t* __restrict__ hB, const bf16_t* __restrict__ Wcat,
    const float* __restrict__ bq, const float* __restrict__ bk, const float* __restrict__ bv,
    float* __restrict__ outV, float* __restrict__ outK, float* __restrict__ outQ,
    bf16_t* __restrict__ qBm)
{
  __shared__ bf16_t sA[2][128 * 64];
  __shared__ bf16_t sB[2][128 * 64];

  const int tid  = threadIdx.x;
  const int wave = tid >> 6, lane = tid & 63;
  const int lr = lane & 15, lg = lane >> 4;
  const int wr = wave >> 1, wc = wave & 1;
  const int row0 = blockIdx.x * 128;
  const int bn   = blockIdx.y;
  const int col0 = bn * 128;            // row offset into Wcat

  f32x4 acc[4][4];
  #pragma unroll
  for (int m = 0; m < 4; m++)
    #pragma unroll
    for (int n = 0; n < 4; n++)
      #pragma unroll
      for (int r = 0; r < 4; r++) acc[m][n][r] = 0.f;

  auto stage = [&](int buf, int k0) {
    #pragma unroll
    for (int j = 0; j < 4; ++j) {
      const int chunk = j * 256 + tid;          // 16B chunk index, row = chunk/8
      const int r = chunk >> 3, c8 = chunk & 7;
      gload16(&hB  [(size_t)(row0 + r) * D_DIM + k0 + c8 * 8],
              &sA[buf][(j * 256 + wave * 64) * 8]);
      gload16(&Wcat[(size_t)(col0 + r) * D_DIM + k0 + c8 * 8],
              &sB[buf][(j * 256 + wave * 64) * 8]);
    }
  };

  stage(0, 0);
  __syncthreads();
  int cur = 0;
  for (int t = 0; t < 16; ++t) {
    if (t + 1 < 16) stage(cur ^ 1, (t + 1) * 64);
    #pragma unroll
    for (int kk = 0; kk < 64; kk += 32) {
      bf16x8 af[4], bfr[4];
      #pragma unroll
      for (int m = 0; m < 4; ++m)
        af[m] = *(const bf16x8*)&sA[cur][(wr * 64 + m * 16 + lr) * 64 + kk + lg * 8];
      #pragma unroll
      for (int n = 0; n < 4; ++n)
        bfr[n] = *(const bf16x8*)&sB[cur][(wc * 64 + n * 16 + lr) * 64 + kk + lg * 8];
      #pragma unroll
      for (int m = 0; m < 4; ++m)
        #pragma unroll
        for (int n = 0; n < 4; ++n)
          acc[m][n] = __builtin_amdgcn_mfma_f32_16x16x32_bf16(af[m], bfr[n], acc[m][n], 0, 0, 0);
    }
    __syncthreads();
    cur ^= 1;
  }

  // epilogue. C frag layout: col = lr, row = lg*4 + reg.
  const int sec    = bn >> 3;                         // 0=q, 1=k, 2=v
  const int colIn0 = (bn & 7) * 128 + wc * 64;        // col within [0,1024)
  const float* bias = (sec == 0) ? bq : (sec == 1 ? bk : bv);
  float bvv[4];
  #pragma unroll
  for (int c = 0; c < 4; c++) bvv[c] = bias[colIn0 + c * 16 + lr];

  #pragma unroll
  for (int m = 0; m < 4; ++m) {
    #pragma unroll
    for (int r = 0; r < 4; ++r) {
      const int gm = row0 + wr * 64 + m * 16 + lg * 4 + r;
      float v[4];
      float ss = 0.f;
      #pragma unroll
      for (int c = 0; c < 4; c++) {
        v[c] = acc[m][c][r] + bvv[c];
        ss += v[c] * v[c];
      }
      if (sec == 2) {
        #pragma unroll
        for (int c = 0; c < 4; c++)
          outV[(size_t)gm * D_DIM + colIn0 + c * 16 + lr] = v[c];
      } else {
        #pragma unroll
        for (int msk = 1; msk < 16; msk <<= 1) ss += __shfl_xor(ss, msk);
        const float rs = 1.0f / sqrtf(ss);
        if (sec == 0) {
          const size_t qrow = (size_t)(gm & 3) * S_LEN + (gm >> 2);  // batch-major
          #pragma unroll
          for (int c = 0; c < 4; c++) {
            const float qn = v[c] * rs;
            outQ[(size_t)gm * D_DIM + colIn0 + c * 16 + lr] = qn;
            qBm[qrow * D_DIM + colIn0 + c * 16 + lr] = (bf16_t)qn;
          }
        } else {
          #pragma unroll
          for (int c = 0; c < 4; c++) {
            float kn = v[c] * rs;
            kn = kn > 0.f ? kn : expm1f(kn);
            outK[(size_t)gm * D_DIM + colIn0 + c * 16 + lr] = kn;
          }
        }
      }
    }
  }
}

// ---------------- stage 2: A[b,n,v,q] partials = sum_s v*k ----------------
// grid (64 = b*16+n, 8 s-chunks), 256 threads
__global__ __launch_bounds__(256) void k_state(
    const float* __restrict__ Kf, const float* __restrict__ Vf,
    float* __restrict__ Apart)
{
  const int bn = blockIdx.x;
  const int ch = blockIdx.y;
  const int b = bn >> 4, n = bn & 15;
  const int tid = threadIdx.x;
  const int ti = tid >> 4, tj = tid & 15;

  __shared__ float sV[32][64];
  __shared__ float sK[32][64];

  float acc[4][4];
  #pragma unroll
  for (int i = 0; i < 4; i++)
    #pragma unroll
    for (int j = 0; j < 4; j++) acc[i][j] = 0.f;

  const int rr = tid >> 3, cc = (tid & 7) * 8;   // 8 elems per thread per step
  for (int s0 = ch * 512; s0 < ch * 512 + 512; s0 += 32) {
    const size_t g = (size_t)((s0 + rr) * B_SZ + b) * D_DIM + n * 64 + cc;
    *(f32x4*)&sV[rr][cc]     = *(const f32x4*)&Vf[g];
    *(f32x4*)&sV[rr][cc + 4] = *(const f32x4*)&Vf[g + 4];
    *(f32x4*)&sK[rr][cc]     = *(const f32x4*)&Kf[g];
    *(f32x4*)&sK[rr][cc + 4] = *(const f32x4*)&Kf[g + 4];
    __syncthreads();
    #pragma unroll
    for (int ss = 0; ss < 32; ss++) {
      f32x4 vv = *(const f32x4*)&sV[ss][ti * 4];
      f32x4 kk = *(const f32x4*)&sK[ss][tj * 4];
      #pragma unroll
      for (int i = 0; i < 4; i++)
        #pragma unroll
        for (int j = 0; j < 4; j++)
          acc[i][j] = fmaf(vv[i], kk[j], acc[i][j]);
    }
    __syncthreads();
  }
  float* ap = Apart + ((size_t)ch * 64 + bn) * 4096;
  #pragma unroll
  for (int i = 0; i < 4; i++)
    #pragma unroll
    for (int j = 0; j < 4; j++)
      ap[(ti * 4 + i) * 64 + tj * 4 + j] = acc[i][j];
}

// ---------------- stage 3: Ct[b][d', n*64+dq] = sum_dv Wo[d',n*64+dv]*A[b,n,dv,dq] ----------------
// grid (64 = b*16+n, 16 d'-tiles), 256 threads
__global__ __launch_bounds__(256) void k_combine(
    const float* __restrict__ Apart, const bf16_t* __restrict__ WoB,
    bf16_t* __restrict__ Ct)
{
  const int bn = blockIdx.x;
  const int dp = blockIdx.y;
  const int b = bn >> 4, n = bn & 15;
  const int tid = threadIdx.x;
  const int ti = tid >> 4, tj = tid & 15;

  __shared__ float sAm[64][65];   // A[dv][dq]
  __shared__ float sW[64][65];    // Wo[d'local][dv]

  #pragma unroll
  for (int p = 0; p < 16; p++) {
    const int idx = tid + p * 256;           // dv*64 + dq
    float s = 0.f;
    #pragma unroll
    for (int c2 = 0; c2 < 8; c2++)
      s += Apart[((size_t)c2 * 64 + bn) * 4096 + idx];
    sAm[idx >> 6][idx & 63] = s;
  }
  {
    const int r = tid >> 2, cv = (tid & 3) * 16;
    bf16x8 w0 = *(const bf16x8*)&WoB[(size_t)(dp * 64 + r) * D_DIM + n * 64 + cv];
    bf16x8 w1 = *(const bf16x8*)&WoB[(size_t)(dp * 64 + r) * D_DIM + n * 64 + cv + 8];
    #pragma unroll
    for (int e = 0; e < 8; e++) {
      sW[r][cv + e]     = (float)w0[e];
      sW[r][cv + 8 + e] = (float)w1[e];
    }
  }
  __syncthreads();

  float acc[4][4];
  #pragma unroll
  for (int i = 0; i < 4; i++)
    #pragma unroll
    for (int j = 0; j < 4; j++) acc[i][j] = 0.f;

  for (int dv = 0; dv < 64; dv++) {
    float w[4], a[4];
    #pragma unroll
    for (int i = 0; i < 4; i++) w[i] = sW[ti * 4 + i][dv];
    #pragma unroll
    for (int j = 0; j < 4; j++) a[j] = sAm[dv][tj * 4 + j];
    #pragma unroll
    for (int i = 0; i < 4; i++)
      #pragma unroll
      for (int j = 0; j < 4; j++)
        acc[i][j] = fmaf(w[i], a[j], acc[i][j]);
  }
  #pragma unroll
  for (int i = 0; i < 4; i++)
    #pragma unroll
    for (int j = 0; j < 4; j++)
      Ct[((size_t)b * D_DIM + dp * 64 + ti * 4 + i) * D_DIM + n * 64 + tj * 4 + j] =
          (bf16_t)acc[i][j];
}

// ---------------- stage 4: out[s*4+b, d'] = qBm[b][s] @ Ct_b^T + bo ----------------
// grid (32, 8, 4=b), 256 threads, 128x128 tile, BK=64, dbuf 2-phase.
__global__ __launch_bounds__(256) void k_final(
    const bf16_t* __restrict__ qBm, const bf16_t* __restrict__ Ct,
    const float* __restrict__ bo, float* __restrict__ outO)
{
  __shared__ bf16_t sA[2][128 * 64];
  __shared__ bf16_t sB[2][128 * 64];

  const int tid  = threadIdx.x;
  const int wave = tid >> 6, lane = tid & 63;
  const int lr = lane & 15, lg = lane >> 4;
  const int wr = wave >> 1, wc = wave & 1;
  const int b    = blockIdx.z;
  const int row0 = blockIdx.x * 128;          // s within batch
  const int col0 = blockIdx.y * 128;          // d'
  const bf16_t* Aq = qBm + (size_t)b * S_LEN * D_DIM;
  const bf16_t* Bc = Ct  + (size_t)b * D_DIM * D_DIM;

  f32x4 acc[4][4];
  #pragma unroll
  for (int m = 0; m < 4; m++)
    #pragma unroll
    for (int n = 0; n < 4; n++)
      #pragma unroll
      for (int r = 0; r < 4; r++) acc[m][n][r] = 0.f;

  auto stage = [&](int buf, int k0) {
    #pragma unroll
    for (int j = 0; j < 4; ++j) {
      const int chunk = j * 256 + tid;
      const int r = chunk >> 3, c8 = chunk & 7;
      gload16(&Aq[(size_t)(row0 + r) * D_DIM + k0 + c8 * 8],
              &sA[buf][(j * 256 + wave * 64) * 8]);
      gload16(&Bc[(size_t)(col0 + r) * D_DIM + k0 + c8 * 8],
              &sB[buf][(j * 256 + wave * 64) * 8]);
    }
  };

  stage(0, 0);
  __syncthreads();
  int cur = 0;
  for (int t = 0; t < 16; ++t) {
    if (t + 1 < 16) stage(cur ^ 1, (t + 1) * 64);
    #pragma unroll
    for (int kk = 0; kk < 64; kk += 32) {
      bf16x8 af[4], bfr[4];
      #pragma unroll
      for (int m = 0; m < 4; ++m)
        af[m] = *(const bf16x8*)&sA[cur][(wr * 64 + m * 16 + lr) * 64 + kk + lg * 8];
      #pragma unroll
      for (int n = 0; n < 4; ++n)
        bfr[n] = *(const bf16x8*)&sB[cur][(wc * 64 + n * 16 + lr) * 64 + kk + lg * 8];
      #pragma unroll
      for (int m = 0; m < 4; ++m)
        #pragma unroll
        for (int n = 0; n < 4; ++n)
          acc[m][n] = __builtin_amdgcn_mfma_f32_16x16x32_bf16(af[m], bfr[n], acc[m][n], 0, 0, 0);
    }
    __syncthreads();
    cur ^= 1;
  }

  #pragma unroll
  for (int m = 0; m < 4; ++m) {
    #pragma unroll
    for (int r = 0; r < 4; ++r) {
      const int gs = row0 + wr * 64 + m * 16 + lg * 4 + r;   // s within batch
      #pragma unroll
      for (int c = 0; c < 4; c++) {
        const int col = col0 + wc * 64 + c * 16 + lr;
        outO[((size_t)gs * B_SZ + b) * D_DIM + col] = acc[m][c][r] + bo[col];
      }
    }
  }
}

extern "C" void kernel_launch(void* const* d_in, const int* in_sizes, int n_in,
                              void* d_out, int out_size, void* d_ws, size_t ws_size,
                              hipStream_t stream) {
  (void)in_sizes; (void)n_in; (void)out_size; (void)ws_size;
  const float* h  = (const float*)d_in[0];
  const float* Wq = (const float*)d_in[1];
  const float* bq = (const float*)d_in[2];
  const float* Wk = (const float*)d_in[3];
  const float* bk = (const float*)d_in[4];
  const float* Wv = (const float*)d_in[5];
  const float* bv = (const float*)d_in[6];
  const float* Wo = (const float*)d_in[7];
  const float* bo = (const float*)d_in[8];

  float* out0 = (float*)d_out;                       // final out (holds V until k_final)
  float* outK = out0 + (size_t)R_ROWS * D_DIM;       // k
  float* outQ = outK + (size_t)R_ROWS * D_DIM;       // q

  char* ws = (char*)d_ws;
  bf16_t* hB    = (bf16_t*)ws;                                 // 32 MB (dead after proj)
  bf16_t* Ct    = (bf16_t*)ws;                                 // 8 MB, reuses hB space
  bf16_t* Wcat  = (bf16_t*)(ws + 33554432);                    // 6 MB: Wq|Wk|Wv rows
  bf16_t* WoB   = (bf16_t*)(ws + 33554432 + 6291456);          // 2 MB
  float*  Apart = (float*)(ws + 41943040);                     // 8 MB
  bf16_t* qBm   = (bf16_t*)(ws + 50331648);                    // 32 MB, batch-major q

  const int nH = R_ROWS * D_DIM;   // 16777216
  const int nW = D_DIM * D_DIM;    // 1048576
  k_cvt<<<nH / 1024, 256, 0, stream>>>(h, hB, nH);
  k_cvt<<<nW / 1024, 256, 0, stream>>>(Wq, Wcat, nW);
  k_cvt<<<nW / 1024, 256, 0, stream>>>(Wk, Wcat + nW, nW);
  k_cvt<<<nW / 1024, 256, 0, stream>>>(Wv, Wcat + 2 * nW, nW);
  k_cvt<<<nW / 1024, 256, 0, stream>>>(Wo, WoB, nW);

  k_proj<<<dim3(R_ROWS / 128, 24), 256, 0, stream>>>(hB, Wcat, bq, bk, bv,
                                                     out0, outK, outQ, qBm);
  k_state<<<dim3(64, 8), 256, 0, stream>>>(outK, out0, Apart);
  k_combine<<<dim3(64, 16), 256, 0, stream>>>(Apart, WoB, Ct);
  k_final<<<dim3(S_LEN / 128, D_DIM / 128, B_SZ), 256, 0, stream>>>(qBm, Ct, bo, out0);
}

// Round 4
// 277.526 us; speedup vs baseline: 2.0070x; 1.2935x over previous
//
#include <hip/hip_runtime.h>
#include <hip/hip_bf16.h>
#include <math.h>

#define S_LEN 4096
#define B_SZ  4
#define D_DIM 1024
#define NHEAD 16
#define R_ROWS (S_LEN * B_SZ)   // 16384

#define AS1 __attribute__((address_space(1)))
#define AS3 __attribute__((address_space(3)))

typedef __bf16 bf16_t;
typedef __attribute__((ext_vector_type(8))) __bf16 bf16x8;
typedef __attribute__((ext_vector_type(4))) __bf16 bf16x4;
typedef __attribute__((ext_vector_type(4))) float  f32x4;

#define MFMA16 __builtin_amdgcn_mfma_f32_16x16x32_bf16

__device__ __forceinline__ void gload16(const bf16_t* g, bf16_t* l) {
  __builtin_amdgcn_global_load_lds((const AS1 unsigned int*)g,
                                   (AS3 unsigned int*)l, 16, 0, 0);
}
__device__ __forceinline__ void hard_barrier() {
  // HW barrier + compiler memory fence, WITHOUT the vmcnt(0)/lgkmcnt(0) drain
  // that __syncthreads() forces.
  asm volatile("s_barrier" ::: "memory");
}

// ---------------- stage 0: fp32 -> bf16 convert ----------------
__global__ void k_cvt(const float* __restrict__ src, bf16_t* __restrict__ dst, int n) {
  int i = (blockIdx.x * 256 + threadIdx.x) * 4;
  if (i >= n) return;
  f32x4 v = *(const f32x4*)(src + i);
  bf16x4 o;
  o[0] = (bf16_t)v[0]; o[1] = (bf16_t)v[1]; o[2] = (bf16_t)v[2]; o[3] = (bf16_t)v[3];
  *(bf16x4*)(dst + i) = o;
}

// =====================================================================
// Counted-vmcnt pipelined NT-GEMM core. C[256,128] block, BK=64, K=1024.
// 512 threads = 8 waves (4 M-waves x 2 N-waves); per-wave 64x64 output.
// 3 LDS buffers: tile t lives in buf t%3; while computing t we stage t+2
// into buf (t+2)%3 == buf of t-1 (free after t-1's closing barrier).
// Closing s_waitcnt vmcnt(6) drains exactly tile t+1's 6 loads (t+2's 6
// stay in flight) -> loads never drained to 0 mid-loop (T4).
// LDS swizzle (T2/G4): 16B-chunk index XOR (row&7), applied to the GLOBAL
// source in staging (linear LDS dest, rule #21) and to read addresses.
// acc[m 0..3][n 0..3]: C row = wr*64+m*16+lg*4+reg, col = wn*64+n*16+lr.
// =====================================================================
template <typename SHA, typename SHB>
__device__ __forceinline__ void gemm_core_256x128(
    const bf16_t* __restrict__ A, const bf16_t* __restrict__ B,
    int row0, int col0, SHA& sA, SHB& sB, f32x4 acc[4][4])
{
  const int tid  = threadIdx.x;
  const int wave = tid >> 6, lane = tid & 63;
  const int lr = lane & 15, lg = lane >> 4;
  const int wr = wave >> 1, wn = wave & 1;
  const int srow = tid >> 3, schunk = tid & 7;
  const int sch_swz = schunk ^ (srow & 7);

  // staging: one call = 8 KB = 64 rows x 64 bf16. j = 64-row block index.
  auto stageA = [&](int buf, int k0, int j) {
    gload16(&A[(size_t)(row0 + j * 64 + srow) * D_DIM + k0 + sch_swz * 8],
            &sA[buf][(j * 64 + wave * 8) * 64]);
  };
  auto stageB = [&](int buf, int k0, int j) {
    gload16(&B[(size_t)(col0 + j * 64 + srow) * D_DIM + k0 + sch_swz * 8],
            &sB[buf][(j * 64 + wave * 8) * 64]);
  };
  auto rdA = [&](int buf, int m, int kk) -> bf16x8 {
    const int r = wr * 64 + m * 16 + lr;
    const int ch = ((kk >> 3) + lg) ^ (r & 7);
    return *(const bf16x8*)&sA[buf][r * 64 + ch * 8];
  };
  auto rdB = [&](int buf, int n, int kk) -> bf16x8 {
    const int r = wn * 64 + n * 16 + lr;
    const int ch = ((kk >> 3) + lg) ^ (r & 7);
    return *(const bf16x8*)&sB[buf][r * 64 + ch * 8];
  };

  #pragma unroll
  for (int m = 0; m < 4; m++)
    #pragma unroll
    for (int n = 0; n < 4; n++)
      #pragma unroll
      for (int r = 0; r < 4; r++) acc[m][n][r] = 0.f;

  // prologue: fully stage tiles 0 and 1 (6 loads each)
  #pragma unroll
  for (int j = 0; j < 4; ++j) stageA(0, 0, j);
  #pragma unroll
  for (int j = 0; j < 2; ++j) stageB(0, 0, j);
  #pragma unroll
  for (int j = 0; j < 4; ++j) stageA(1, 64, j);
  #pragma unroll
  for (int j = 0; j < 2; ++j) stageB(1, 64, j);
  asm volatile("s_waitcnt vmcnt(6)" ::: "memory");   // tile 0 resident
  hard_barrier();

  for (int t = 0; t < 16; ++t) {
    const int c  = t % 3;
    const int cn = (t + 2) % 3;
    const int kn = (t + 2) * 64;
    const bool st = (t < 14);

    // B fragments for the whole tile (8 reads) + A fragments for phase 0 (4)
    bf16x8 bfr[4][2];
    #pragma unroll
    for (int n = 0; n < 4; ++n) { bfr[n][0] = rdB(c, n, 0); bfr[n][1] = rdB(c, n, 32); }
    bf16x8 a00 = rdA(c, 0, 0), a01 = rdA(c, 0, 32);
    bf16x8 a10 = rdA(c, 1, 0), a11 = rdA(c, 1, 32);
    if (st) { stageA(cn, kn, 0); stageA(cn, kn, 1); stageB(cn, kn, 0); }
    hard_barrier();
    asm volatile("s_waitcnt lgkmcnt(0)" ::: "memory");
    __builtin_amdgcn_sched_barrier(0);
    __builtin_amdgcn_s_setprio(1);
    #pragma unroll
    for (int n = 0; n < 4; ++n) {
      acc[0][n] = MFMA16(a00, bfr[n][0], acc[0][n], 0, 0, 0);
      acc[0][n] = MFMA16(a01, bfr[n][1], acc[0][n], 0, 0, 0);
      acc[1][n] = MFMA16(a10, bfr[n][0], acc[1][n], 0, 0, 0);
      acc[1][n] = MFMA16(a11, bfr[n][1], acc[1][n], 0, 0, 0);
    }
    __builtin_amdgcn_s_setprio(0);
    hard_barrier();

    // phase 1: m = 2,3
    bf16x8 a20 = rdA(c, 2, 0), a21 = rdA(c, 2, 32);
    bf16x8 a30 = rdA(c, 3, 0), a31 = rdA(c, 3, 32);
    if (st) { stageA(cn, kn, 2); stageA(cn, kn, 3); stageB(cn, kn, 1); }
    hard_barrier();
    asm volatile("s_waitcnt lgkmcnt(0)" ::: "memory");
    __builtin_amdgcn_sched_barrier(0);
    __builtin_amdgcn_s_setprio(1);
    #pragma unroll
    for (int n = 0; n < 4; ++n) {
      acc[2][n] = MFMA16(a20, bfr[n][0], acc[2][n], 0, 0, 0);
      acc[2][n] = MFMA16(a21, bfr[n][1], acc[2][n], 0, 0, 0);
      acc[3][n] = MFMA16(a30, bfr[n][0], acc[3][n], 0, 0, 0);
      acc[3][n] = MFMA16(a31, bfr[n][1], acc[3][n], 0, 0, 0);
    }
    __builtin_amdgcn_s_setprio(0);
    if (t < 14)       asm volatile("s_waitcnt vmcnt(6)" ::: "memory");  // tile t+1 resident
    else if (t == 14) asm volatile("s_waitcnt vmcnt(0)" ::: "memory");  // tile 15 resident
    hard_barrier();
  }
}

// ---------------- stage 1: fused QKV projection ----------------
// C[16384, 3072] = h @ Wcat^T. grid (64, 24). panel 0..7 q / 8..15 k / 16..23 v.
__global__ __launch_bounds__(512, 2) void k_proj(
    const bf16_t* __restrict__ hB, const bf16_t* __restrict__ Wcat,
    const float* __restrict__ bq, const float* __restrict__ bk, const float* __restrict__ bv,
    bf16_t* __restrict__ outVb, float* __restrict__ outK, float* __restrict__ outQ,
    bf16_t* __restrict__ qBm)
{
  __shared__ bf16_t sA[3][256 * 64];   // 96 KB
  __shared__ bf16_t sB[3][128 * 64];   // 48 KB

  const int tid  = threadIdx.x;
  const int wave = tid >> 6, lane = tid & 63;
  const int lr = lane & 15, lg = lane >> 4;
  const int wr = wave >> 1, wn = wave & 1;
  const int row0 = blockIdx.x * 256;
  const int bn   = blockIdx.y;

  f32x4 acc[4][4];
  gemm_core_256x128(hB, Wcat, row0, bn * 128, sA, sB, acc);

  const int sec = bn >> 3;                                // 0=q 1=k 2=v
  const int hc0 = (bn & 7) * 128 + wn * 64;               // col base in [0,1024)
  const float* bias = (sec == 0) ? bq : (sec == 1 ? bk : bv);
  float bvv[4];
  #pragma unroll
  for (int n = 0; n < 4; n++) bvv[n] = bias[hc0 + n * 16 + lr];

  #pragma unroll
  for (int m = 0; m < 4; ++m) {
    #pragma unroll
    for (int r = 0; r < 4; ++r) {
      const int gm = row0 + wr * 64 + m * 16 + lg * 4 + r;
      float v[4];
      float ss = 0.f;
      #pragma unroll
      for (int n = 0; n < 4; n++) {
        v[n] = acc[m][n][r] + bvv[n];
        ss += v[n] * v[n];
      }
      if (sec == 2) {
        #pragma unroll
        for (int n = 0; n < 4; n++)
          outVb[(size_t)gm * D_DIM + hc0 + n * 16 + lr] = (bf16_t)v[n];
      } else {
        #pragma unroll
        for (int msk = 1; msk < 16; msk <<= 1) ss += __shfl_xor(ss, msk);
        const float rs = 1.0f / sqrtf(ss);
        if (sec == 0) {
          const size_t qrow = (size_t)(gm & 3) * S_LEN + (gm >> 2);   // batch-major
          #pragma unroll
          for (int n = 0; n < 4; n++) {
            const float qn = v[n] * rs;
            outQ[(size_t)gm * D_DIM + hc0 + n * 16 + lr] = qn;
            qBm[qrow * D_DIM + hc0 + n * 16 + lr] = (bf16_t)qn;
          }
        } else {
          #pragma unroll
          for (int n = 0; n < 4; n++) {
            float kn = v[n] * rs;
            kn = kn > 0.f ? kn : expm1f(kn);
            outK[(size_t)gm * D_DIM + hc0 + n * 16 + lr] = kn;
          }
        }
      }
    }
  }
}

// ---------------- stage 2: A[b,n,v,q] partials = sum_s v*k ----------------
// grid (64 = b*16+n, 8 s-chunks), 256 threads. V is bf16, K is fp32.
__global__ __launch_bounds__(256) void k_state(
    const float* __restrict__ Kf, const bf16_t* __restrict__ Vb,
    float* __restrict__ Apart)
{
  const int bn = blockIdx.x;
  const int ch = blockIdx.y;
  const int b = bn >> 4, n = bn & 15;
  const int tid = threadIdx.x;
  const int ti = tid >> 4, tj = tid & 15;

  __shared__ float sV[32][64];
  __shared__ float sK[32][64];

  float acc[4][4];
  #pragma unroll
  for (int i = 0; i < 4; i++)
    #pragma unroll
    for (int j = 0; j < 4; j++) acc[i][j] = 0.f;

  const int rr = tid >> 3, cc = (tid & 7) * 8;
  for (int s0 = ch * 512; s0 < ch * 512 + 512; s0 += 32) {
    const size_t g = (size_t)((s0 + rr) * B_SZ + b) * D_DIM + n * 64 + cc;
    bf16x8 v8 = *(const bf16x8*)&Vb[g];
    #pragma unroll
    for (int e = 0; e < 8; e++) sV[rr][cc + e] = (float)v8[e];
    *(f32x4*)&sK[rr][cc]     = *(const f32x4*)&Kf[g];
    *(f32x4*)&sK[rr][cc + 4] = *(const f32x4*)&Kf[g + 4];
    __syncthreads();
    #pragma unroll
    for (int ss = 0; ss < 32; ss++) {
      f32x4 vv = *(const f32x4*)&sV[ss][ti * 4];
      f32x4 kk = *(const f32x4*)&sK[ss][tj * 4];
      #pragma unroll
      for (int i = 0; i < 4; i++)
        #pragma unroll
        for (int j = 0; j < 4; j++)
          acc[i][j] = fmaf(vv[i], kk[j], acc[i][j]);
    }
    __syncthreads();
  }
  float* ap = Apart + ((size_t)ch * 64 + bn) * 4096;
  #pragma unroll
  for (int i = 0; i < 4; i++)
    #pragma unroll
    for (int j = 0; j < 4; j++)
      ap[(ti * 4 + i) * 64 + tj * 4 + j] = acc[i][j];
}

// ---------------- stage 3: Ct[b][d', n*64+dq] = sum_dv Wo[d',n*64+dv]*A[b,n,dv,dq] ----------------
__global__ __launch_bounds__(256) void k_combine(
    const float* __restrict__ Apart, const bf16_t* __restrict__ WoB,
    bf16_t* __restrict__ Ct)
{
  const int bn = blockIdx.x;
  const int dp = blockIdx.y;
  const int b = bn >> 4, n = bn & 15;
  const int tid = threadIdx.x;
  const int ti = tid >> 4, tj = tid & 15;

  __shared__ float sAm[64][65];
  __shared__ float sW[64][65];

  #pragma unroll
  for (int p = 0; p < 16; p++) {
    const int idx = tid + p * 256;
    float s = 0.f;
    #pragma unroll
    for (int c2 = 0; c2 < 8; c2++)
      s += Apart[((size_t)c2 * 64 + bn) * 4096 + idx];
    sAm[idx >> 6][idx & 63] = s;
  }
  {
    const int r = tid >> 2, cv = (tid & 3) * 16;
    bf16x8 w0 = *(const bf16x8*)&WoB[(size_t)(dp * 64 + r) * D_DIM + n * 64 + cv];
    bf16x8 w1 = *(const bf16x8*)&WoB[(size_t)(dp * 64 + r) * D_DIM + n * 64 + cv + 8];
    #pragma unroll
    for (int e = 0; e < 8; e++) {
      sW[r][cv + e]     = (float)w0[e];
      sW[r][cv + 8 + e] = (float)w1[e];
    }
  }
  __syncthreads();

  float acc[4][4];
  #pragma unroll
  for (int i = 0; i < 4; i++)
    #pragma unroll
    for (int j = 0; j < 4; j++) acc[i][j] = 0.f;

  for (int dv = 0; dv < 64; dv++) {
    float w[4], a[4];
    #pragma unroll
    for (int i = 0; i < 4; i++) w[i] = sW[ti * 4 + i][dv];
    #pragma unroll
    for (int j = 0; j < 4; j++) a[j] = sAm[dv][tj * 4 + j];
    #pragma unroll
    for (int i = 0; i < 4; i++)
      #pragma unroll
      for (int j = 0; j < 4; j++)
        acc[i][j] = fmaf(w[i], a[j], acc[i][j]);
  }
  #pragma unroll
  for (int i = 0; i < 4; i++)
    #pragma unroll
    for (int j = 0; j < 4; j++)
      Ct[((size_t)b * D_DIM + dp * 64 + ti * 4 + i) * D_DIM + n * 64 + tj * 4 + j] =
          (bf16_t)acc[i][j];
}

// ---------------- stage 4: out[s*4+b, d'] = qBm[b] @ Ct_b^T + bo ----------------
// grid (16, 8, 4), 512 threads.
__global__ __launch_bounds__(512, 2) void k_final(
    const bf16_t* __restrict__ qBm, const bf16_t* __restrict__ Ct,
    const float* __restrict__ bo, float* __restrict__ outO)
{
  __shared__ bf16_t sA[3][256 * 64];
  __shared__ bf16_t sB[3][128 * 64];

  const int tid  = threadIdx.x;
  const int wave = tid >> 6, lane = tid & 63;
  const int lr = lane & 15, lg = lane >> 4;
  const int wr = wave >> 1, wn = wave & 1;
  const int b    = blockIdx.z;
  const int row0 = blockIdx.x * 256;
  const int col0 = blockIdx.y * 128;

  f32x4 acc[4][4];
  gemm_core_256x128(qBm + (size_t)b * S_LEN * D_DIM, Ct + (size_t)b * D_DIM * D_DIM,
                    row0, col0, sA, sB, acc);

  #pragma unroll
  for (int m = 0; m < 4; ++m) {
    #pragma unroll
    for (int r = 0; r < 4; ++r) {
      const int gs = row0 + wr * 64 + m * 16 + lg * 4 + r;
      #pragma unroll
      for (int n = 0; n < 4; n++) {
        const int col = col0 + wn * 64 + n * 16 + lr;
        outO[((size_t)gs * B_SZ + b) * D_DIM + col] = acc[m][n][r] + bo[col];
      }
    }
  }
}

extern "C" void kernel_launch(void* const* d_in, const int* in_sizes, int n_in,
                              void* d_out, int out_size, void* d_ws, size_t ws_size,
                              hipStream_t stream) {
  (void)in_sizes; (void)n_in; (void)out_size; (void)ws_size;
  const float* h  = (const float*)d_in[0];
  const float* Wq = (const float*)d_in[1];
  const float* bq = (const float*)d_in[2];
  const float* Wk = (const float*)d_in[3];
  const float* bk = (const float*)d_in[4];
  const float* Wv = (const float*)d_in[5];
  const float* bv = (const float*)d_in[6];
  const float* Wo = (const float*)d_in[7];
  const float* bo = (const float*)d_in[8];

  float* out0 = (float*)d_out;                       // final out
  float* outK = out0 + (size_t)R_ROWS * D_DIM;       // k
  float* outQ = outK + (size_t)R_ROWS * D_DIM;       // q
  bf16_t* vB  = (bf16_t*)d_out;                      // V (bf16) parked in out0's space

  char* ws = (char*)d_ws;
  bf16_t* hB    = (bf16_t*)ws;                                 // 32 MB (dead after proj)
  bf16_t* Ct    = (bf16_t*)ws;                                 // 8 MB, reuses hB space
  bf16_t* Wcat  = (bf16_t*)(ws + 33554432);                    // 6 MB: Wq|Wk|Wv rows
  bf16_t* WoB   = (bf16_t*)(ws + 33554432 + 6291456);          // 2 MB
  float*  Apart = (float*)(ws + 41943040);                     // 8 MB
  bf16_t* qBm   = (bf16_t*)(ws + 50331648);                    // 32 MB, batch-major q

  const int nH = R_ROWS * D_DIM;   // 16777216
  const int nW = D_DIM * D_DIM;    // 1048576
  k_cvt<<<nH / 1024, 256, 0, stream>>>(h, hB, nH);
  k_cvt<<<nW / 1024, 256, 0, stream>>>(Wq, Wcat, nW);
  k_cvt<<<nW / 1024, 256, 0, stream>>>(Wk, Wcat + nW, nW);
  k_cvt<<<nW / 1024, 256, 0, stream>>>(Wv, Wcat + 2 * nW, nW);
  k_cvt<<<nW / 1024, 256, 0, stream>>>(Wo, WoB, nW);

  k_proj<<<dim3(R_ROWS / 256, 24), 512, 0, stream>>>(hB, Wcat, bq, bk, bv,
                                                     vB, outK, outQ, qBm);
  k_state<<<dim3(64, 8), 256, 0, stream>>>(outK, vB, Apart);
  k_combine<<<dim3(64, 16), 256, 0, stream>>>(Apart, WoB, Ct);
  k_final<<<dim3(S_LEN / 256, D_DIM / 128, B_SZ), 512, 0, stream>>>(qBm, Ct, bo, out0);
}

// Round 5
// 265.298 us; speedup vs baseline: 2.0995x; 1.0461x over previous
//
#include <hip/hip_runtime.h>
#include <hip/hip_bf16.h>
#include <math.h>

#define S_LEN 4096
#define B_SZ  4
#define D_DIM 1024
#define NHEAD 16
#define R_ROWS (S_LEN * B_SZ)   // 16384

#define AS1 __attribute__((address_space(1)))
#define AS3 __attribute__((address_space(3)))

typedef __bf16 bf16_t;
typedef __attribute__((ext_vector_type(8))) __bf16 bf16x8;
typedef __attribute__((ext_vector_type(4))) __bf16 bf16x4;
typedef __attribute__((ext_vector_type(4))) float  f32x4;

#define MFMA16 __builtin_amdgcn_mfma_f32_16x16x32_bf16

__device__ __forceinline__ void gload16(const bf16_t* g, bf16_t* l) {
  __builtin_amdgcn_global_load_lds((const AS1 unsigned int*)g,
                                   (AS3 unsigned int*)l, 16, 0, 0);
}
__device__ __forceinline__ void hard_barrier() {
  // HW barrier + compiler fence, WITHOUT __syncthreads()'s vmcnt(0) drain.
  asm volatile("s_barrier" ::: "memory");
}

// ---------------- stage 0: fp32 -> bf16 convert ----------------
__global__ void k_cvt(const float* __restrict__ src, bf16_t* __restrict__ dst, int n) {
  int i = (blockIdx.x * 256 + threadIdx.x) * 4;
  if (i >= n) return;
  f32x4 v = *(const f32x4*)(src + i);
  bf16x4 o;
  o[0] = (bf16_t)v[0]; o[1] = (bf16_t)v[1]; o[2] = (bf16_t)v[2]; o[3] = (bf16_t)v[3];
  *(bf16x4*)(dst + i) = o;
}

// =====================================================================
// Counted-vmcnt pipelined NT-GEMM core, m201 geometry.
// C[256,256] block, BK=32, K=1024 (32 K-tiles). 512 threads = 8 waves
// (2 M-waves x 4 N-waves); per-wave output 128x64 (8 M-frags x 4 N-frags),
// acc = 32 x f32x4 = 128 VGPR.
// 3 LDS buffers (96 KB): compute tile t from buf t%3 while staging tile
// t+2 into buf (t+2)%3 (= buf of t-1, freed at t-1's closing barrier).
// Stage of one tile = 4 gload16/thread (2 A + 2 B); closing wait
// vmcnt(4) leaves t+2's 4 loads in flight, t+1 resident (T4: never 0).
// Swizzle (T2, rule #21): tile row = 32 bf16 = 4 16B-chunks; LDS slot
// (row, sc) holds global chunk sc ^ (row&3); gload_lds dest linear,
// global source pre-swizzled, reads XOR the same involution ->
// ds_read_b128 at the 8-lanes-per-4-bank floor (conflict-free).
// =====================================================================
__device__ __forceinline__ void gemm_core_256(
    const bf16_t* __restrict__ A, const bf16_t* __restrict__ B,
    int row0, int col0,
    bf16_t (&sA)[3][8192], bf16_t (&sB)[3][8192], f32x4 (&acc)[8][4])
{
  const int tid  = threadIdx.x;
  const int wave = tid >> 6, lane = tid & 63;
  const int lr = lane & 15, lg = lane >> 4;
  const int wr = wave >> 2, wn = wave & 3;
  const int grow = tid >> 2;                      // staging row within 128-half
  const int gch  = (tid & 3) ^ (grow & 3);        // pre-swizzled source chunk

  auto stageA = [&](int buf, int k0, int j) {
    gload16(&A[(size_t)(row0 + j * 128 + grow) * D_DIM + k0 + gch * 8],
            &sA[buf][(j * 512 + wave * 64) * 8]);
  };
  auto stageB = [&](int buf, int k0, int j) {
    gload16(&B[(size_t)(col0 + j * 128 + grow) * D_DIM + k0 + gch * 8],
            &sB[buf][(j * 512 + wave * 64) * 8]);
  };

  // loop-invariant swizzled read offsets (registers; constant-indexed)
  int aoff[8], boff[4];
  #pragma unroll
  for (int m = 0; m < 8; m++) {
    const int r = wr * 128 + m * 16 + lr;
    aoff[m] = r * 32 + (lg ^ (r & 3)) * 8;
  }
  #pragma unroll
  for (int n = 0; n < 4; n++) {
    const int r = wn * 64 + n * 16 + lr;
    boff[n] = r * 32 + (lg ^ (r & 3)) * 8;
  }

  #pragma unroll
  for (int m = 0; m < 8; m++)
    #pragma unroll
    for (int n = 0; n < 4; n++)
      #pragma unroll
      for (int r = 0; r < 4; r++) acc[m][n][r] = 0.f;

  // prologue: stage tiles 0 and 1 (4 loads each)
  stageA(0, 0, 0); stageA(0, 0, 1); stageB(0, 0, 0); stageB(0, 0, 1);
  stageA(1, 32, 0); stageA(1, 32, 1); stageB(1, 32, 0); stageB(1, 32, 1);
  asm volatile("s_waitcnt vmcnt(4)" ::: "memory");   // tile 0 resident
  hard_barrier();

  for (int t = 0; t < 32; ++t) {
    const int c  = t % 3;
    const int cn = (t + 2) % 3;
    const int kn = (t + 2) * 32;
    const bool st = (t < 30);

    // phase 0: m = 0..3 x all n
    bf16x8 bfr[4], afr[4];
    #pragma unroll
    for (int n = 0; n < 4; ++n) bfr[n] = *(const bf16x8*)&sB[c][boff[n]];
    #pragma unroll
    for (int m = 0; m < 4; ++m) afr[m] = *(const bf16x8*)&sA[c][aoff[m]];
    if (st) { stageA(cn, kn, 0); stageA(cn, kn, 1); }
    hard_barrier();
    asm volatile("s_waitcnt lgkmcnt(0)" ::: "memory");
    __builtin_amdgcn_sched_barrier(0);
    __builtin_amdgcn_s_setprio(1);
    #pragma unroll
    for (int m = 0; m < 4; ++m)
      #pragma unroll
      for (int n = 0; n < 4; ++n)
        acc[m][n] = MFMA16(afr[m], bfr[n], acc[m][n], 0, 0, 0);
    __builtin_amdgcn_s_setprio(0);
    hard_barrier();

    // phase 1: m = 4..7 x all n
    #pragma unroll
    for (int m = 0; m < 4; ++m) afr[m] = *(const bf16x8*)&sA[c][aoff[m + 4]];
    if (st) { stageB(cn, kn, 0); stageB(cn, kn, 1); }
    hard_barrier();
    asm volatile("s_waitcnt lgkmcnt(0)" ::: "memory");
    __builtin_amdgcn_sched_barrier(0);
    __builtin_amdgcn_s_setprio(1);
    #pragma unroll
    for (int m = 0; m < 4; ++m)
      #pragma unroll
      for (int n = 0; n < 4; ++n)
        acc[m + 4][n] = MFMA16(afr[m], bfr[n], acc[m + 4][n], 0, 0, 0);
    __builtin_amdgcn_s_setprio(0);
    if (t < 30)       asm volatile("s_waitcnt vmcnt(4)" ::: "memory");  // t+1 resident
    else if (t == 30) asm volatile("s_waitcnt vmcnt(0)" ::: "memory");  // tile 31 resident
    hard_barrier();
  }
}

// ---------------- stage 1: fused QKV projection ----------------
// C[16384, 3072] = h @ Wcat^T. grid (64, 12). by 0..3 q / 4..7 k / 8..11 v.
// Each wave's 64-col group == one head's full norm group.
__global__ __launch_bounds__(512, 2) void k_proj(
    const bf16_t* __restrict__ hB, const bf16_t* __restrict__ Wcat,
    const float* __restrict__ bq, const float* __restrict__ bk, const float* __restrict__ bv,
    bf16_t* __restrict__ outVb, float* __restrict__ outK, float* __restrict__ outQ,
    bf16_t* __restrict__ qBm)
{
  __shared__ bf16_t sA[3][8192];   // 48 KB
  __shared__ bf16_t sB[3][8192];   // 48 KB

  const int tid  = threadIdx.x;
  const int wave = tid >> 6, lane = tid & 63;
  const int lr = lane & 15, lg = lane >> 4;
  const int wr = wave >> 2, wn = wave & 3;
  const int row0 = blockIdx.x * 256;
  const int by   = blockIdx.y;

  f32x4 acc[8][4];
  gemm_core_256(hB, Wcat, row0, by * 256, sA, sB, acc);

  const int sec = by >> 2;                                // 0=q 1=k 2=v
  const int hc0 = (by & 3) * 256 + wn * 64;               // col base in [0,1024)
  const float* bias = (sec == 0) ? bq : (sec == 1 ? bk : bv);
  float bvv[4];
  #pragma unroll
  for (int n = 0; n < 4; n++) bvv[n] = bias[hc0 + n * 16 + lr];

  #pragma unroll
  for (int m = 0; m < 8; ++m) {
    #pragma unroll
    for (int r = 0; r < 4; ++r) {
      const int gm = row0 + wr * 128 + m * 16 + lg * 4 + r;
      float v[4];
      float ss = 0.f;
      #pragma unroll
      for (int n = 0; n < 4; n++) {
        v[n] = acc[m][n][r] + bvv[n];
        ss += v[n] * v[n];
      }
      if (sec == 2) {
        #pragma unroll
        for (int n = 0; n < 4; n++)
          outVb[(size_t)gm * D_DIM + hc0 + n * 16 + lr] = (bf16_t)v[n];
      } else {
        #pragma unroll
        for (int msk = 1; msk < 16; msk <<= 1) ss += __shfl_xor(ss, msk);
        const float rs = 1.0f / sqrtf(ss);
        if (sec == 0) {
          const size_t qrow = (size_t)(gm & 3) * S_LEN + (gm >> 2);   // batch-major
          #pragma unroll
          for (int n = 0; n < 4; n++) {
            const float qn = v[n] * rs;
            outQ[(size_t)gm * D_DIM + hc0 + n * 16 + lr] = qn;
            qBm[qrow * D_DIM + hc0 + n * 16 + lr] = (bf16_t)qn;
          }
        } else {
          #pragma unroll
          for (int n = 0; n < 4; n++) {
            float kn = v[n] * rs;
            kn = kn > 0.f ? kn : expm1f(kn);
            outK[(size_t)gm * D_DIM + hc0 + n * 16 + lr] = kn;
          }
        }
      }
    }
  }
}

// ---------------- stage 2: A[b,n,v,q] partials = sum_s v*k ----------------
// grid (64 = b*16+n, 8 s-chunks), 256 threads. V is bf16, K is fp32.
__global__ __launch_bounds__(256) void k_state(
    const float* __restrict__ Kf, const bf16_t* __restrict__ Vb,
    float* __restrict__ Apart)
{
  const int bn = blockIdx.x;
  const int ch = blockIdx.y;
  const int b = bn >> 4, n = bn & 15;
  const int tid = threadIdx.x;
  const int ti = tid >> 4, tj = tid & 15;

  __shared__ float sV[32][64];
  __shared__ float sK[32][64];

  float acc[4][4];
  #pragma unroll
  for (int i = 0; i < 4; i++)
    #pragma unroll
    for (int j = 0; j < 4; j++) acc[i][j] = 0.f;

  const int rr = tid >> 3, cc = (tid & 7) * 8;
  for (int s0 = ch * 512; s0 < ch * 512 + 512; s0 += 32) {
    const size_t g = (size_t)((s0 + rr) * B_SZ + b) * D_DIM + n * 64 + cc;
    bf16x8 v8 = *(const bf16x8*)&Vb[g];
    #pragma unroll
    for (int e = 0; e < 8; e++) sV[rr][cc + e] = (float)v8[e];
    *(f32x4*)&sK[rr][cc]     = *(const f32x4*)&Kf[g];
    *(f32x4*)&sK[rr][cc + 4] = *(const f32x4*)&Kf[g + 4];
    __syncthreads();
    #pragma unroll
    for (int ss = 0; ss < 32; ss++) {
      f32x4 vv = *(const f32x4*)&sV[ss][ti * 4];
      f32x4 kk = *(const f32x4*)&sK[ss][tj * 4];
      #pragma unroll
      for (int i = 0; i < 4; i++)
        #pragma unroll
        for (int j = 0; j < 4; j++)
          acc[i][j] = fmaf(vv[i], kk[j], acc[i][j]);
    }
    __syncthreads();
  }
  float* ap = Apart + ((size_t)ch * 64 + bn) * 4096;
  #pragma unroll
  for (int i = 0; i < 4; i++)
    #pragma unroll
    for (int j = 0; j < 4; j++)
      ap[(ti * 4 + i) * 64 + tj * 4 + j] = acc[i][j];
}

// ---------------- stage 3: Ct[b][d', n*64+dq] = sum_dv Wo[d',n*64+dv]*A[b,n,dv,dq] ----------------
__global__ __launch_bounds__(256) void k_combine(
    const float* __restrict__ Apart, const bf16_t* __restrict__ WoB,
    bf16_t* __restrict__ Ct)
{
  const int bn = blockIdx.x;
  const int dp = blockIdx.y;
  const int b = bn >> 4, n = bn & 15;
  const int tid = threadIdx.x;
  const int ti = tid >> 4, tj = tid & 15;

  __shared__ float sAm[64][65];
  __shared__ float sW[64][65];

  #pragma unroll
  for (int p = 0; p < 16; p++) {
    const int idx = tid + p * 256;
    float s = 0.f;
    #pragma unroll
    for (int c2 = 0; c2 < 8; c2++)
      s += Apart[((size_t)c2 * 64 + bn) * 4096 + idx];
    sAm[idx >> 6][idx & 63] = s;
  }
  {
    const int r = tid >> 2, cv = (tid & 3) * 16;
    bf16x8 w0 = *(const bf16x8*)&WoB[(size_t)(dp * 64 + r) * D_DIM + n * 64 + cv];
    bf16x8 w1 = *(const bf16x8*)&WoB[(size_t)(dp * 64 + r) * D_DIM + n * 64 + cv + 8];
    #pragma unroll
    for (int e = 0; e < 8; e++) {
      sW[r][cv + e]     = (float)w0[e];
      sW[r][cv + 8 + e] = (float)w1[e];
    }
  }
  __syncthreads();

  float acc[4][4];
  #pragma unroll
  for (int i = 0; i < 4; i++)
    #pragma unroll
    for (int j = 0; j < 4; j++) acc[i][j] = 0.f;

  for (int dv = 0; dv < 64; dv++) {
    float w[4], a[4];
    #pragma unroll
    for (int i = 0; i < 4; i++) w[i] = sW[ti * 4 + i][dv];
    #pragma unroll
    for (int j = 0; j < 4; j++) a[j] = sAm[dv][tj * 4 + j];
    #pragma unroll
    for (int i = 0; i < 4; i++)
      #pragma unroll
      for (int j = 0; j < 4; j++)
        acc[i][j] = fmaf(w[i], a[j], acc[i][j]);
  }
  #pragma unroll
  for (int i = 0; i < 4; i++)
    #pragma unroll
    for (int j = 0; j < 4; j++)
      Ct[((size_t)b * D_DIM + dp * 64 + ti * 4 + i) * D_DIM + n * 64 + tj * 4 + j] =
          (bf16_t)acc[i][j];
}

// ---------------- stage 4: out[s*4+b, d'] = qBm[b] @ Ct_b^T + bo ----------------
// grid (16, 4, 4), 512 threads.
__global__ __launch_bounds__(512, 2) void k_final(
    const bf16_t* __restrict__ qBm, const bf16_t* __restrict__ Ct,
    const float* __restrict__ bo, float* __restrict__ outO)
{
  __shared__ bf16_t sA[3][8192];
  __shared__ bf16_t sB[3][8192];

  const int tid  = threadIdx.x;
  const int wave = tid >> 6, lane = tid & 63;
  const int lr = lane & 15, lg = lane >> 4;
  const int wr = wave >> 2, wn = wave & 3;
  const int b    = blockIdx.z;
  const int row0 = blockIdx.x * 256;
  const int col0 = blockIdx.y * 256;

  f32x4 acc[8][4];
  gemm_core_256(qBm + (size_t)b * S_LEN * D_DIM, Ct + (size_t)b * D_DIM * D_DIM,
                row0, col0, sA, sB, acc);

  #pragma unroll
  for (int m = 0; m < 8; ++m) {
    #pragma unroll
    for (int r = 0; r < 4; ++r) {
      const int gs = row0 + wr * 128 + m * 16 + lg * 4 + r;
      #pragma unroll
      for (int n = 0; n < 4; n++) {
        const int col = col0 + wn * 64 + n * 16 + lr;
        outO[((size_t)gs * B_SZ + b) * D_DIM + col] = acc[m][n][r] + bo[col];
      }
    }
  }
}

extern "C" void kernel_launch(void* const* d_in, const int* in_sizes, int n_in,
                              void* d_out, int out_size, void* d_ws, size_t ws_size,
                              hipStream_t stream) {
  (void)in_sizes; (void)n_in; (void)out_size; (void)ws_size;
  const float* h  = (const float*)d_in[0];
  const float* Wq = (const float*)d_in[1];
  const float* bq = (const float*)d_in[2];
  const float* Wk = (const float*)d_in[3];
  const float* bk = (const float*)d_in[4];
  const float* Wv = (const float*)d_in[5];
  const float* bv = (const float*)d_in[6];
  const float* Wo = (const float*)d_in[7];
  const float* bo = (const float*)d_in[8];

  float* out0 = (float*)d_out;                       // final out
  float* outK = out0 + (size_t)R_ROWS * D_DIM;       // k
  float* outQ = outK + (size_t)R_ROWS * D_DIM;       // q
  bf16_t* vB  = (bf16_t*)d_out;                      // V (bf16) parked in out0's space

  char* ws = (char*)d_ws;
  bf16_t* hB    = (bf16_t*)ws;                                 // 32 MB (dead after proj)
  bf16_t* Ct    = (bf16_t*)ws;                                 // 8 MB, reuses hB space
  bf16_t* Wcat  = (bf16_t*)(ws + 33554432);                    // 6 MB: Wq|Wk|Wv rows
  bf16_t* WoB   = (bf16_t*)(ws + 33554432 + 6291456);          // 2 MB
  float*  Apart = (float*)(ws + 41943040);                     // 8 MB
  bf16_t* qBm   = (bf16_t*)(ws + 50331648);                    // 32 MB, batch-major q

  const int nH = R_ROWS * D_DIM;   // 16777216
  const int nW = D_DIM * D_DIM;    // 1048576
  k_cvt<<<nH / 1024, 256, 0, stream>>>(h, hB, nH);
  k_cvt<<<nW / 1024, 256, 0, stream>>>(Wq, Wcat, nW);
  k_cvt<<<nW / 1024, 256, 0, stream>>>(Wk, Wcat + nW, nW);
  k_cvt<<<nW / 1024, 256, 0, stream>>>(Wv, Wcat + 2 * nW, nW);
  k_cvt<<<nW / 1024, 256, 0, stream>>>(Wo, WoB, nW);

  k_proj<<<dim3(R_ROWS / 256, 12), 512, 0, stream>>>(hB, Wcat, bq, bk, bv,
                                                     vB, outK, outQ, qBm);
  k_state<<<dim3(64, 8), 256, 0, stream>>>(outK, vB, Apart);
  k_combine<<<dim3(64, 16), 256, 0, stream>>>(Apart, WoB, Ct);
  k_final<<<dim3(S_LEN / 256, D_DIM / 256, B_SZ), 512, 0, stream>>>(qBm, Ct, bo, out0);
}

// Round 6
// 254.410 us; speedup vs baseline: 2.1894x; 1.0428x over previous
//
#include <hip/hip_runtime.h>
#include <hip/hip_bf16.h>
#include <math.h>

#define S_LEN 4096
#define B_SZ  4
#define D_DIM 1024
#define NHEAD 16
#define R_ROWS (S_LEN * B_SZ)   // 16384

#define AS1 __attribute__((address_space(1)))
#define AS3 __attribute__((address_space(3)))

typedef __bf16 bf16_t;
typedef __attribute__((ext_vector_type(8))) __bf16 bf16x8;
typedef __attribute__((ext_vector_type(4))) __bf16 bf16x4;
typedef __attribute__((ext_vector_type(4))) float  f32x4;

#define MFMA16 __builtin_amdgcn_mfma_f32_16x16x32_bf16

__device__ __forceinline__ void gload16(const bf16_t* g, bf16_t* l) {
  __builtin_amdgcn_global_load_lds((const AS1 unsigned int*)g,
                                   (AS3 unsigned int*)l, 16, 0, 0);
}

#define BAR asm volatile("s_barrier" ::: "memory")
#define LGKM0 do { asm volatile("s_waitcnt lgkmcnt(0)" ::: "memory"); \
                   __builtin_amdgcn_sched_barrier(0); } while (0)

// read 4 m-frags x 2 kk from an A-half base
#define RD_A(dst, ap, mlo) \
  _Pragma("unroll") for (int mm = 0; mm < 4; ++mm) \
    _Pragma("unroll") for (int kx = 0; kx < 2; ++kx) \
      dst[mm][kx] = *(const bf16x8*)&ap[offA[(mlo) + mm][kx]];
// read 2 n-frags x 2 kk from a B-half base
#define RD_B(dst, bp, nlo) \
  _Pragma("unroll") for (int nn = 0; nn < 2; ++nn) \
    _Pragma("unroll") for (int kx = 0; kx < 2; ++kx) \
      dst[nn][kx] = *(const bf16x8*)&bp[offB[(nlo) + nn][kx]];
// one C-quadrant x K=64: 16 MFMA, setprio-wrapped (T5)
#define QUAD(mb, nb, AF, BF) \
  do { __builtin_amdgcn_s_setprio(1); \
  _Pragma("unroll") for (int mm = 0; mm < 4; ++mm) \
    _Pragma("unroll") for (int nn = 0; nn < 2; ++nn) { \
      acc[(mb)+mm][(nb)+nn] = MFMA16(AF[mm][0], BF[nn][0], acc[(mb)+mm][(nb)+nn], 0, 0, 0); \
      acc[(mb)+mm][(nb)+nn] = MFMA16(AF[mm][1], BF[nn][1], acc[(mb)+mm][(nb)+nn], 0, 0, 0); } \
  __builtin_amdgcn_s_setprio(0); } while (0)

// ---------------- stage 0: fp32 -> bf16 convert ----------------
__global__ void k_cvt(const float* __restrict__ src, bf16_t* __restrict__ dst, int n) {
  int i = (blockIdx.x * 256 + threadIdx.x) * 4;
  if (i >= n) return;
  f32x4 v = *(const f32x4*)(src + i);
  bf16x4 o;
  o[0] = (bf16_t)v[0]; o[1] = (bf16_t)v[1]; o[2] = (bf16_t)v[2]; o[3] = (bf16_t)v[3];
  *(bf16x4*)(dst + i) = o;
}

// =====================================================================
// m201-style 8-phase NT-GEMM core. C[256,256], BK=64, K=1024 (16 K-tiles,
// 8 iters x 2 K-tiles). 512 threads = 8 waves (2M x 4N), per-wave 128x64.
// LDS 128 KB: sA[buf][half][128x64], buf = K-tile parity (in-place restage).
// Quadrant order per tile: (m0-3,n0-1),(m4-7,n0-1),(m0-3,n2-3),(m4-7,n2-3)
//  -> A-half reads retire at P2, B-half at P3; restaging P3..P5 / P7..P8
//     targets only retired halves (issue after the last reader's barrier).
// Waits (counted, never 0 mid-loop): vmcnt(6) end-P4, vmcnt(8) end-P8.
//  invariant: at iter start 8 loads outstanding (prev P7+P8 = buf1 tile);
//  P4 wait drains them (needed at P5); P8 wait drains this iter's buf0
//  stages (needed at next P1). Prologue: 16 loads, vmcnt(8).
// Swizzle (T2, rule #21): 16B-chunk ^= (row&7); pre-swizzled global source,
// linear gload_lds dest, same XOR on ds_read -> 2 lanes/bank (free).
// =====================================================================
__device__ __forceinline__ void gemm_core_8ph(
    const bf16_t* __restrict__ A, const bf16_t* __restrict__ B,
    int row0, int col0,
    bf16_t (&sA)[2][2][8192], bf16_t (&sB)[2][2][8192], f32x4 (&acc)[8][4])
{
  const int tid  = threadIdx.x;
  const int wave = tid >> 6, lane = tid & 63;
  const int lr = lane & 15, lg = lane >> 4;
  const int wr = wave >> 2, wn = wave & 3;
  const int grow = tid >> 3;                  // staging row in 64-row stripe
  const int gsw  = (tid & 7) ^ (grow & 7);    // pre-swizzled source chunk

  auto stA = [&](int buf, int half, int k0) {
    #pragma unroll
    for (int j = 0; j < 2; ++j)
      gload16(&A[(size_t)(row0 + half * 128 + j * 64 + grow) * D_DIM + k0 + gsw * 8],
              &sA[buf][half][(j * 64 + wave * 8) * 64]);
  };
  auto stB = [&](int buf, int half, int k0) {
    #pragma unroll
    for (int j = 0; j < 2; ++j)
      gload16(&B[(size_t)(col0 + half * 128 + j * 64 + grow) * D_DIM + k0 + gsw * 8],
              &sB[buf][half][(j * 64 + wave * 8) * 64]);
  };

  // swizzled read offsets (bf16 elem) within a [128][64] half
  int offA[8][2], offB[4][2];
  #pragma unroll
  for (int m = 0; m < 8; ++m) {
    const int r = m * 16 + lr;
    #pragma unroll
    for (int kx = 0; kx < 2; ++kx)
      offA[m][kx] = r * 64 + (((kx << 2) + lg) ^ (r & 7)) * 8;
  }
  #pragma unroll
  for (int n = 0; n < 4; ++n) {
    const int r = (wn & 1) * 64 + n * 16 + lr;
    #pragma unroll
    for (int kx = 0; kx < 2; ++kx)
      offB[n][kx] = r * 64 + (((kx << 2) + lg) ^ (r & 7)) * 8;
  }
  const bf16_t* a0 = &sA[0][wr][0];
  const bf16_t* a1 = &sA[1][wr][0];
  const bf16_t* b0 = &sB[0][wn >> 1][0];
  const bf16_t* b1 = &sB[1][wn >> 1][0];

  #pragma unroll
  for (int m = 0; m < 8; m++)
    #pragma unroll
    for (int n = 0; n < 4; n++)
      #pragma unroll
      for (int r = 0; r < 4; r++) acc[m][n][r] = 0.f;

  // prologue: tiles 0 (buf0, k=0) and 1 (buf1, k=64)
  stA(0, 0, 0);  stA(0, 1, 0);  stB(0, 0, 0);  stB(0, 1, 0);
  stA(1, 0, 64); stA(1, 1, 64); stB(1, 0, 64); stB(1, 1, 64);
  asm volatile("s_waitcnt vmcnt(8)" ::: "memory");   // buf0 resident
  BAR;

  bf16x8 af03[4][2], af47[4][2], bf01[2][2], bf23[2][2];

  #pragma unroll 1
  for (int i = 0; i < 8; ++i) {
    const bool last = (i == 7);
    const int kn0 = (i + 1) * 128, kn1 = kn0 + 64;

    // ---- tile t0 (buf0) ----
    // P1
    RD_A(af03, a0, 0); RD_B(bf01, b0, 0);
    BAR; LGKM0; QUAD(0, 0, af03, bf01); BAR;
    // P2  (A-half reads retire here)
    RD_A(af47, a0, 4);
    BAR; LGKM0; QUAD(4, 0, af47, bf01); BAR;
    // P3  (B-half reads retire here; buf0.A.h0 free since P2)
    RD_B(bf23, b0, 2);
    if (!last) stA(0, 0, kn0);
    BAR; LGKM0; QUAD(0, 2, af03, bf23); BAR;
    // P4
    if (!last) { stA(0, 1, kn0); stB(0, 0, kn0); }
    BAR; QUAD(4, 2, af47, bf23);
    if (!last) asm volatile("s_waitcnt vmcnt(6)" ::: "memory");  // buf1 resident
    else       asm volatile("s_waitcnt vmcnt(0)" ::: "memory");
    BAR;

    // ---- tile t1 (buf1) ----
    // P5
    RD_A(af03, a1, 0); RD_B(bf01, b1, 0);
    if (!last) stB(0, 1, kn0);
    BAR; LGKM0; QUAD(0, 0, af03, bf01); BAR;
    // P6
    RD_A(af47, a1, 4);
    BAR; LGKM0; QUAD(4, 0, af47, bf01); BAR;
    // P7
    RD_B(bf23, b1, 2);
    if (!last) stA(1, 0, kn1);
    BAR; LGKM0; QUAD(0, 2, af03, bf23); BAR;
    // P8
    if (!last) { stA(1, 1, kn1); stB(1, 0, kn1); stB(1, 1, kn1); }
    BAR; QUAD(4, 2, af47, bf23);
    if (!last) asm volatile("s_waitcnt vmcnt(8)" ::: "memory");  // buf0 resident
    BAR;
  }
}

// ---------------- stage 1: fused QKV projection ----------------
// C[16384, 3072] = h @ Wcat^T. grid (64, 12). by 0..3 q / 4..7 k / 8..11 v.
// Each wave's 64-col group == one head's full norm group.
__global__ __launch_bounds__(512, 2) void k_proj(
    const bf16_t* __restrict__ hB, const bf16_t* __restrict__ Wcat,
    const float* __restrict__ bq, const float* __restrict__ bk, const float* __restrict__ bv,
    bf16_t* __restrict__ outVb, float* __restrict__ outK, float* __restrict__ outQ,
    bf16_t* __restrict__ qBm)
{
  __shared__ bf16_t sA[2][2][8192];   // 64 KB
  __shared__ bf16_t sB[2][2][8192];   // 64 KB

  const int tid  = threadIdx.x;
  const int wave = tid >> 6, lane = tid & 63;
  const int lr = lane & 15, lg = lane >> 4;
  const int wr = wave >> 2, wn = wave & 3;
  const int row0 = blockIdx.x * 256;
  const int by   = blockIdx.y;

  f32x4 acc[8][4];
  gemm_core_8ph(hB, Wcat, row0, by * 256, sA, sB, acc);

  const int sec = by >> 2;                                // 0=q 1=k 2=v
  const int hc0 = (by & 3) * 256 + wn * 64;               // col base in [0,1024)
  const float* bias = (sec == 0) ? bq : (sec == 1 ? bk : bv);
  float bvv[4];
  #pragma unroll
  for (int n = 0; n < 4; n++) bvv[n] = bias[hc0 + n * 16 + lr];

  #pragma unroll
  for (int m = 0; m < 8; ++m) {
    #pragma unroll
    for (int r = 0; r < 4; ++r) {
      const int gm = row0 + wr * 128 + m * 16 + lg * 4 + r;
      float v[4];
      float ss = 0.f;
      #pragma unroll
      for (int n = 0; n < 4; n++) {
        v[n] = acc[m][n][r] + bvv[n];
        ss += v[n] * v[n];
      }
      if (sec == 2) {
        #pragma unroll
        for (int n = 0; n < 4; n++)
          outVb[(size_t)gm * D_DIM + hc0 + n * 16 + lr] = (bf16_t)v[n];
      } else {
        #pragma unroll
        for (int msk = 1; msk < 16; msk <<= 1) ss += __shfl_xor(ss, msk);
        const float rs = 1.0f / sqrtf(ss);
        if (sec == 0) {
          const size_t qrow = (size_t)(gm & 3) * S_LEN + (gm >> 2);   // batch-major
          #pragma unroll
          for (int n = 0; n < 4; n++) {
            const float qn = v[n] * rs;
            outQ[(size_t)gm * D_DIM + hc0 + n * 16 + lr] = qn;
            qBm[qrow * D_DIM + hc0 + n * 16 + lr] = (bf16_t)qn;
          }
        } else {
          #pragma unroll
          for (int n = 0; n < 4; n++) {
            float kn = v[n] * rs;
            kn = kn > 0.f ? kn : expm1f(kn);
            outK[(size_t)gm * D_DIM + hc0 + n * 16 + lr] = kn;
          }
        }
      }
    }
  }
}

// ---------------- stage 2: A[b,n,v,q] partials = sum_s v*k ----------------
// grid (64 = b*16+n, 8 s-chunks), 256 threads. V is bf16, K is fp32.
__global__ __launch_bounds__(256) void k_state(
    const float* __restrict__ Kf, const bf16_t* __restrict__ Vb,
    float* __restrict__ Apart)
{
  const int bn = blockIdx.x;
  const int ch = blockIdx.y;
  const int b = bn >> 4, n = bn & 15;
  const int tid = threadIdx.x;
  const int ti = tid >> 4, tj = tid & 15;

  __shared__ float sV[32][64];
  __shared__ float sK[32][64];

  float acc[4][4];
  #pragma unroll
  for (int i = 0; i < 4; i++)
    #pragma unroll
    for (int j = 0; j < 4; j++) acc[i][j] = 0.f;

  const int rr = tid >> 3, cc = (tid & 7) * 8;
  for (int s0 = ch * 512; s0 < ch * 512 + 512; s0 += 32) {
    const size_t g = (size_t)((s0 + rr) * B_SZ + b) * D_DIM + n * 64 + cc;
    bf16x8 v8 = *(const bf16x8*)&Vb[g];
    #pragma unroll
    for (int e = 0; e < 8; e++) sV[rr][cc + e] = (float)v8[e];
    *(f32x4*)&sK[rr][cc]     = *(const f32x4*)&Kf[g];
    *(f32x4*)&sK[rr][cc + 4] = *(const f32x4*)&Kf[g + 4];
    __syncthreads();
    #pragma unroll
    for (int ss = 0; ss < 32; ss++) {
      f32x4 vv = *(const f32x4*)&sV[ss][ti * 4];
      f32x4 kk = *(const f32x4*)&sK[ss][tj * 4];
      #pragma unroll
      for (int i = 0; i < 4; i++)
        #pragma unroll
        for (int j = 0; j < 4; j++)
          acc[i][j] = fmaf(vv[i], kk[j], acc[i][j]);
    }
    __syncthreads();
  }
  float* ap = Apart + ((size_t)ch * 64 + bn) * 4096;
  #pragma unroll
  for (int i = 0; i < 4; i++)
    #pragma unroll
    for (int j = 0; j < 4; j++)
      ap[(ti * 4 + i) * 64 + tj * 4 + j] = acc[i][j];
}

// ---------------- stage 3: Ct[b][d', n*64+dq] = sum_dv Wo[d',n*64+dv]*A[b,n,dv,dq] ----------------
__global__ __launch_bounds__(256) void k_combine(
    const float* __restrict__ Apart, const bf16_t* __restrict__ WoB,
    bf16_t* __restrict__ Ct)
{
  const int bn = blockIdx.x;
  const int dp = blockIdx.y;
  const int b = bn >> 4, n = bn & 15;
  const int tid = threadIdx.x;
  const int ti = tid >> 4, tj = tid & 15;

  __shared__ float sAm[64][65];
  __shared__ float sW[64][65];

  #pragma unroll
  for (int p = 0; p < 16; p++) {
    const int idx = tid + p * 256;
    float s = 0.f;
    #pragma unroll
    for (int c2 = 0; c2 < 8; c2++)
      s += Apart[((size_t)c2 * 64 + bn) * 4096 + idx];
    sAm[idx >> 6][idx & 63] = s;
  }
  {
    const int r = tid >> 2, cv = (tid & 3) * 16;
    bf16x8 w0 = *(const bf16x8*)&WoB[(size_t)(dp * 64 + r) * D_DIM + n * 64 + cv];
    bf16x8 w1 = *(const bf16x8*)&WoB[(size_t)(dp * 64 + r) * D_DIM + n * 64 + cv + 8];
    #pragma unroll
    for (int e = 0; e < 8; e++) {
      sW[r][cv + e]     = (float)w0[e];
      sW[r][cv + 8 + e] = (float)w1[e];
    }
  }
  __syncthreads();

  float acc[4][4];
  #pragma unroll
  for (int i = 0; i < 4; i++)
    #pragma unroll
    for (int j = 0; j < 4; j++) acc[i][j] = 0.f;

  for (int dv = 0; dv < 64; dv++) {
    float w[4], a[4];
    #pragma unroll
    for (int i = 0; i < 4; i++) w[i] = sW[ti * 4 + i][dv];
    #pragma unroll
    for (int j = 0; j < 4; j++) a[j] = sAm[dv][tj * 4 + j];
    #pragma unroll
    for (int i = 0; i < 4; i++)
      #pragma unroll
      for (int j = 0; j < 4; j++)
        acc[i][j] = fmaf(w[i], a[j], acc[i][j]);
  }
  #pragma unroll
  for (int i = 0; i < 4; i++)
    #pragma unroll
    for (int j = 0; j < 4; j++)
      Ct[((size_t)b * D_DIM + dp * 64 + ti * 4 + i) * D_DIM + n * 64 + tj * 4 + j] =
          (bf16_t)acc[i][j];
}

// ---------------- stage 4: out[s*4+b, d'] = qBm[b] @ Ct_b^T + bo ----------------
// grid (16, 4, 4), 512 threads.
__global__ __launch_bounds__(512, 2) void k_final(
    const bf16_t* __restrict__ qBm, const bf16_t* __restrict__ Ct,
    const float* __restrict__ bo, float* __restrict__ outO)
{
  __shared__ bf16_t sA[2][2][8192];
  __shared__ bf16_t sB[2][2][8192];

  const int tid  = threadIdx.x;
  const int wave = tid >> 6, lane = tid & 63;
  const int lr = lane & 15, lg = lane >> 4;
  const int wr = wave >> 2, wn = wave & 3;
  const int b    = blockIdx.z;
  const int row0 = blockIdx.x * 256;
  const int col0 = blockIdx.y * 256;

  f32x4 acc[8][4];
  gemm_core_8ph(qBm + (size_t)b * S_LEN * D_DIM, Ct + (size_t)b * D_DIM * D_DIM,
                row0, col0, sA, sB, acc);

  #pragma unroll
  for (int m = 0; m < 8; ++m) {
    #pragma unroll
    for (int r = 0; r < 4; ++r) {
      const int gs = row0 + wr * 128 + m * 16 + lg * 4 + r;
      #pragma unroll
      for (int n = 0; n < 4; n++) {
        const int col = col0 + wn * 64 + n * 16 + lr;
        outO[((size_t)gs * B_SZ + b) * D_DIM + col] = acc[m][n][r] + bo[col];
      }
    }
  }
}

extern "C" void kernel_launch(void* const* d_in, const int* in_sizes, int n_in,
                              void* d_out, int out_size, void* d_ws, size_t ws_size,
                              hipStream_t stream) {
  (void)in_sizes; (void)n_in; (void)out_size; (void)ws_size;
  const float* h  = (const float*)d_in[0];
  const float* Wq = (const float*)d_in[1];
  const float* bq = (const float*)d_in[2];
  const float* Wk = (const float*)d_in[3];
  const float* bk = (const float*)d_in[4];
  const float* Wv = (const float*)d_in[5];
  const float* bv = (const float*)d_in[6];
  const float* Wo = (const float*)d_in[7];
  const float* bo = (const float*)d_in[8];

  float* out0 = (float*)d_out;                       // final out
  float* outK = out0 + (size_t)R_ROWS * D_DIM;       // k
  float* outQ = outK + (size_t)R_ROWS * D_DIM;       // q
  bf16_t* vB  = (bf16_t*)d_out;                      // V (bf16) parked in out0's space

  char* ws = (char*)d_ws;
  bf16_t* hB    = (bf16_t*)ws;                                 // 32 MB (dead after proj)
  bf16_t* Ct    = (bf16_t*)ws;                                 // 8 MB, reuses hB space
  bf16_t* Wcat  = (bf16_t*)(ws + 33554432);                    // 6 MB: Wq|Wk|Wv rows
  bf16_t* WoB   = (bf16_t*)(ws + 33554432 + 6291456);          // 2 MB
  float*  Apart = (float*)(ws + 41943040);                     // 8 MB
  bf16_t* qBm   = (bf16_t*)(ws + 50331648);                    // 32 MB, batch-major q

  const int nH = R_ROWS * D_DIM;   // 16777216
  const int nW = D_DIM * D_DIM;    // 1048576
  k_cvt<<<nH / 1024, 256, 0, stream>>>(h, hB, nH);
  k_cvt<<<nW / 1024, 256, 0, stream>>>(Wq, Wcat, nW);
  k_cvt<<<nW / 1024, 256, 0, stream>>>(Wk, Wcat + nW, nW);
  k_cvt<<<nW / 1024, 256, 0, stream>>>(Wv, Wcat + 2 * nW, nW);
  k_cvt<<<nW / 1024, 256, 0, stream>>>(Wo, WoB, nW);

  k_proj<<<dim3(R_ROWS / 256, 12), 512, 0, stream>>>(hB, Wcat, bq, bk, bv,
                                                     vB, outK, outQ, qBm);
  k_state<<<dim3(64, 8), 256, 0, stream>>>(outK, vB, Apart);
  k_combine<<<dim3(64, 16), 256, 0, stream>>>(Apart, WoB, Ct);
  k_final<<<dim3(S_LEN / 256, D_DIM / 256, B_SZ), 512, 0, stream>>>(qBm, Ct, bo, out0);
}